// Round 4
// baseline (2095.479 us; speedup 1.0000x reference)
//
#include <hip/hip_runtime.h>
#include <math.h>

typedef unsigned short u16;
typedef __bf16 bf16x8 __attribute__((ext_vector_type(8)));
typedef float f32x4 __attribute__((ext_vector_type(4)));

#define DEVI static __device__ __forceinline__

DEVI float b2f(u16 u) { union { unsigned int i; float f; } w; w.i = ((unsigned int)u) << 16; return w.f; }
DEVI u16 f2b(float f) {
  union { float f; unsigned int i; } w; w.f = f;
  unsigned int r = (w.i + 0x7FFFu + ((w.i >> 16) & 1u)) >> 16;
  return (u16)r;
}

// ---------------- f32 -> bf16 weight conversion ----------------
__global__ void conv_f2b_kernel(const float* __restrict__ s, u16* __restrict__ d, int n) {
  int i = blockIdx.x * 256 + threadIdx.x;
  int st = gridDim.x * 256;
  for (; i < n; i += st) d[i] = f2b(s[i]);
}

// ---------------- LayerNorm (+optional rel_bias), f32 in -> bf16 out ----------------
template<int ADD_REL>
__global__ __launch_bounds__(256) void ln_kernel(
    const float* __restrict__ x, const float* __restrict__ w, const float* __restrict__ bb,
    const float* __restrict__ rel, u16* __restrict__ out) {
  int row = blockIdx.x;            // 0..16383 = b*4096 + l
  int t = threadIdx.x;             // 256
  const float* xr = x + (size_t)row * 512;
  float v0 = xr[t], v1 = xr[t + 256];
  float s = v0 + v1, ss = v0 * v0 + v1 * v1;
#pragma unroll
  for (int o = 32; o > 0; o >>= 1) { s += __shfl_down(s, o); ss += __shfl_down(ss, o); }
  __shared__ float rs[4], rss[4];
  int lane = t & 63, wid = t >> 6;
  if (lane == 0) { rs[wid] = s; rss[wid] = ss; }
  __syncthreads();
  s = rs[0] + rs[1] + rs[2] + rs[3];
  ss = rss[0] + rss[1] + rss[2] + rss[3];
  float mu = s * (1.0f / 512.0f);
  float inv = rsqrtf(ss * (1.0f / 512.0f) - mu * mu + 1e-5f);
  float o0 = (v0 - mu) * inv * w[t] + bb[t];
  float o1 = (v1 - mu) * inv * w[t + 256] + bb[t + 256];
  if (ADD_REL) {
    const float* rr = rel + (size_t)(row & 4095) * 512;
    o0 += rr[t]; o1 += rr[t + 256];
  }
  u16* orow = out + (size_t)row * 512;
  orow[t] = f2b(o0);
  orow[t + 256] = f2b(o1);
}

// ---------------- GEMM: C[M,N] = A[M,K] @ W[N,K]^T + bias, bf16 MFMA ----------------
// EPI: 0=qkv scatter, 1=proj+residual->f32, 2=gelu->bf16, 3=fc2+residual->f32 (d_out)
template<int EPI>
__global__ __launch_bounds__(256) void gemm_bt_kernel(
    const u16* __restrict__ A, const u16* __restrict__ W,
    const float* __restrict__ bias, int M, int N, int K,
    const float* __restrict__ resid, u16* __restrict__ outb,
    u16* __restrict__ q_out, u16* __restrict__ k_out, u16* __restrict__ v_out,
    float* __restrict__ outf) {
  constexpr int LDT = 40;                      // 32 + 8 pad (80B rows, 16B aligned)
  __shared__ u16 As[128 * LDT];
  __shared__ u16 Bs[128 * LDT];
  int bn = blockIdx.x, bm = blockIdx.y;
  int m0 = bm * 128, n0 = bn * 128;
  int t = threadIdx.x, lane = t & 63, wid = t >> 6;
  int wr = (wid >> 1) * 64, wc = (wid & 1) * 64;    // wave -> 64x64 quadrant
  int fr = lane & 15, fk = (lane >> 4) * 8;
  f32x4 acc[4][4] = {};
  for (int k0 = 0; k0 < K; k0 += 32) {
#pragma unroll
    for (int i = 0; i < 2; ++i) {               // stage 128x32 A and B tiles
      int seg = t + i * 256;
      int r = seg >> 2, c = (seg & 3) * 8;
      *(uint4*)&As[r * LDT + c] = *(const uint4*)&A[(size_t)(m0 + r) * K + k0 + c];
      *(uint4*)&Bs[r * LDT + c] = *(const uint4*)&W[(size_t)(n0 + r) * K + k0 + c];
    }
    __syncthreads();
    bf16x8 af[4], bfr[4];
#pragma unroll
    for (int i = 0; i < 4; ++i) af[i] = *(const bf16x8*)&As[(wr + i * 16 + fr) * LDT + fk];
#pragma unroll
    for (int j = 0; j < 4; ++j) bfr[j] = *(const bf16x8*)&Bs[(wc + j * 16 + fr) * LDT + fk];
#pragma unroll
    for (int i = 0; i < 4; ++i)
#pragma unroll
      for (int j = 0; j < 4; ++j)
        acc[i][j] = __builtin_amdgcn_mfma_f32_16x16x32_bf16(af[i], bfr[j], acc[i][j], 0, 0, 0);
    __syncthreads();
  }
  int fq = lane >> 4;
#pragma unroll
  for (int i = 0; i < 4; ++i) {
#pragma unroll
    for (int j = 0; j < 4; ++j) {
#pragma unroll
      for (int jj = 0; jj < 4; ++jj) {
        int gm = m0 + wr + i * 16 + fq * 4 + jj;
        int gn = n0 + wc + j * 16 + fr;
        float v = acc[i][j][jj] + bias[gn];
        if (EPI == 0) {
          // qkv: n -> (which, head, d); write (b,h,l,d) contiguous
          int which = gn >> 9, head = (gn >> 6) & 7, dd = gn & 63;
          int b = gm >> 12, l = gm & 4095;
          u16* dst = (which == 0) ? q_out : (which == 1) ? k_out : v_out;
          dst[(((size_t)(b * 8 + head) * 4096) + l) * 64 + dd] = f2b(v);
        } else if (EPI == 1) {
          size_t idx = (size_t)gm * 512 + gn;
          outf[idx] = v + resid[idx];
        } else if (EPI == 2) {
          float g = 0.5f * v * (1.0f + erff(v * 0.70710678118654752f));
          outb[(size_t)gm * (size_t)N + gn] = f2b(g);
        } else {
          size_t idx = (size_t)gm * 512 + gn;
          outf[idx] = v + resid[idx];               // f32 store to d_out
        }
      }
    }
  }
}

// ---------------- RMSNorm over HD=64, in-place on bf16 q/k ----------------
__global__ __launch_bounds__(256) void rms_kernel(u16* __restrict__ qk, const float* __restrict__ g) {
  int row = blockIdx.x * 4 + (threadIdx.x >> 6);   // (b*8+h)*4096 + l
  int d = threadIdx.x & 63;
  size_t idx = (size_t)row * 64 + d;
  float v = b2f(qk[idx]);
  float ss = v * v;
#pragma unroll
  for (int o = 32; o > 0; o >>= 1) ss += __shfl_xor(ss, o);
  float nrm = fmaxf(sqrtf(ss), 1e-12f);
  int head = (row >> 12) & 7;
  qk[idx] = f2b(v / nrm * 8.0f * g[head * 64 + d]);
}

// ---------------- Lightning attention, SIMPLE VALU f32 version ----------------
// One block per (b,h); 256 threads; chunk of 128 rows in LDS; kv state f32 in LDS.
// Thread t owns output row r=t>>1, e-half e0=(t&1)*32.
__global__ __launch_bounds__(256) void attn_simple_kernel(
    const u16* __restrict__ q, const u16* __restrict__ k, const u16* __restrict__ v,
    u16* __restrict__ o) {
  __shared__ float kf[128][64];
  __shared__ float vf[128][64];
  __shared__ float kvf[64][64];
  __shared__ float kdecs[128];
  int bh = blockIdx.x;
  float sl = exp2f(-(float)((bh & 7) + 1));        // slope for head h = 2^-(h+1)
  int t = threadIdx.x;
  const u16* qb = q + (size_t)bh * 262144;
  const u16* kb = k + (size_t)bh * 262144;
  const u16* vb = v + (size_t)bh * 262144;
  u16* ob = o + (size_t)bh * 262144;
  {
    float* kvp = &kvf[0][0];
    for (int i = t; i < 4096; i += 256) kvp[i] = 0.0f;
    for (int i = t; i < 128; i += 256) kdecs[i] = expf(-sl * (float)(128 - i));
  }
  float cdec = expf(-sl * 128.0f);
  int r = t >> 1, e0 = (t & 1) * 32;
  for (int c = 0; c < 32; ++c) {
    int l0 = c * 128;
    __syncthreads();   // prev chunk's kv updates visible; kf/vf readers done
    for (int i = t; i < 1024; i += 256) {
      int rr = i >> 3, cc = (i & 7) * 8;
      uint4 kp = *(const uint4*)&kb[((size_t)(l0 + rr)) * 64 + cc];
      uint4 vp = *(const uint4*)&vb[((size_t)(l0 + rr)) * 64 + cc];
      const u16* kpp = (const u16*)&kp;
      const u16* vpp = (const u16*)&vp;
#pragma unroll
      for (int e = 0; e < 8; ++e) { kf[rr][cc + e] = b2f(kpp[e]); vf[rr][cc + e] = b2f(vpp[e]); }
    }
    float qr[64];
#pragma unroll
    for (int g = 0; g < 8; ++g) {
      uint4 qp = *(const uint4*)&qb[((size_t)(l0 + r)) * 64 + g * 8];
      const u16* qpp = (const u16*)&qp;
#pragma unroll
      for (int e = 0; e < 8; ++e) qr[g * 8 + e] = b2f(qpp[e]);
    }
    __syncthreads();
    f32x4 acc4[8];
#pragma unroll
    for (int g = 0; g < 8; ++g) acc4[g] = f32x4{0.f, 0.f, 0.f, 0.f};
    // intra: j <= r
    for (int j = 0; j <= r; ++j) {
      float s = 0.f;
#pragma unroll
      for (int g = 0; g < 16; ++g) {
        f32x4 kk4 = *(const f32x4*)&kf[j][g * 4];
        s += qr[g * 4 + 0] * kk4[0] + qr[g * 4 + 1] * kk4[1]
           + qr[g * 4 + 2] * kk4[2] + qr[g * 4 + 3] * kk4[3];
      }
      s *= expf(-sl * (float)(r - j));
#pragma unroll
      for (int g = 0; g < 8; ++g) {
        f32x4 vv = *(const f32x4*)&vf[j][e0 + g * 4];
        acc4[g] += s * vv;
      }
    }
    // inter: q_dec[r] * (q . kv)
    float qdr = expf(-sl * (float)r);
#pragma unroll
    for (int d = 0; d < 64; ++d) {
      float qv = qdr * qr[d];
#pragma unroll
      for (int g = 0; g < 8; ++g) {
        f32x4 kv4 = *(const f32x4*)&kvf[d][e0 + g * 4];
        acc4[g] += qv * kv4;
      }
    }
#pragma unroll
    for (int g = 0; g < 8; ++g)
#pragma unroll
      for (int e = 0; e < 4; ++e)
        ob[((size_t)(l0 + r)) * 64 + e0 + g * 4 + e] = f2b(acc4[g][e]);
    __syncthreads();   // all kvf reads (inter) done before update
    // kv update: thread owns kvf[dd][eb..eb+16)
    int dd = t >> 2, eb = (t & 3) * 16;
    f32x4 upd4[4];
#pragma unroll
    for (int g = 0; g < 4; ++g) upd4[g] = f32x4{0.f, 0.f, 0.f, 0.f};
    for (int j = 0; j < 128; ++j) {
      float kj = kdecs[j] * kf[j][dd];
#pragma unroll
      for (int g = 0; g < 4; ++g) {
        f32x4 vv = *(const f32x4*)&vf[j][eb + g * 4];
        upd4[g] += kj * vv;
      }
    }
#pragma unroll
    for (int g = 0; g < 4; ++g)
#pragma unroll
      for (int e = 0; e < 4; ++e)
        kvf[dd][eb + g * 4 + e] = cdec * kvf[dd][eb + g * 4 + e] + upd4[g][e];
  }
}

extern "C" void kernel_launch(void* const* d_in, const int* in_sizes, int n_in,
                              void* d_out, int out_size, void* d_ws, size_t ws_size,
                              hipStream_t stream) {
  // Inputs are f32 (per reference dtypes; confirmed by in_npz size ~= f32 total).
  // Output is f32 (reference output dtype).
  const float* x      = (const float*)d_in[0];
  const float* ln1_w  = (const float*)d_in[1];
  const float* ln1_b  = (const float*)d_in[2];
  const float* rel    = (const float*)d_in[3];
  const float* qkv_w  = (const float*)d_in[4];
  const float* qkv_b  = (const float*)d_in[5];
  const float* gq     = (const float*)d_in[6];
  const float* gk     = (const float*)d_in[7];
  const float* proj_w = (const float*)d_in[8];
  const float* proj_b = (const float*)d_in[9];
  const float* ln2_w  = (const float*)d_in[10];
  const float* ln2_b  = (const float*)d_in[11];
  const float* fc1_w  = (const float*)d_in[12];
  const float* fc1_b  = (const float*)d_in[13];
  const float* fc2_w  = (const float*)d_in[14];
  const float* fc2_b  = (const float*)d_in[15];

  char* ws = (char*)d_ws;
  size_t off = 0;
  auto alloc = [&](size_t bytes) { char* p = ws + off; off += (bytes + 255) & ~(size_t)255; return p; };
  u16* w_qkv  = (u16*)alloc((size_t)1536 * 512 * 2);
  u16* w_proj = (u16*)alloc((size_t)512 * 512 * 2);
  u16* w_fc1  = (u16*)alloc((size_t)2048 * 512 * 2);
  u16* w_fc2  = (u16*)alloc((size_t)512 * 2048 * 2);
  u16* h_buf  = (u16*)alloc((size_t)16384 * 512 * 2);   // ln1 out; reused for ln2 out
  u16* q_buf  = (u16*)alloc((size_t)8388608 * 2);
  u16* k_buf  = (u16*)alloc((size_t)8388608 * 2);
  u16* v_buf  = (u16*)alloc((size_t)8388608 * 2);
  u16* o_buf  = (u16*)alloc((size_t)8388608 * 2);
  float* x2   = (float*)alloc((size_t)8388608 * 4);
  u16* mid    = q_buf;   // 16384x2048 bf16 overlays q..o (dead after attention/proj)

  conv_f2b_kernel<<<512, 256, 0, stream>>>(qkv_w, w_qkv, 1536 * 512);
  conv_f2b_kernel<<<512, 256, 0, stream>>>(proj_w, w_proj, 512 * 512);
  conv_f2b_kernel<<<512, 256, 0, stream>>>(fc1_w, w_fc1, 2048 * 512);
  conv_f2b_kernel<<<512, 256, 0, stream>>>(fc2_w, w_fc2, 512 * 2048);

  ln_kernel<1><<<16384, 256, 0, stream>>>(x, ln1_w, ln1_b, rel, h_buf);

  gemm_bt_kernel<0><<<dim3(12, 128), 256, 0, stream>>>(h_buf, w_qkv, qkv_b, 16384, 1536, 512,
      nullptr, nullptr, q_buf, k_buf, v_buf, nullptr);

  rms_kernel<<<32768, 256, 0, stream>>>(q_buf, gq);
  rms_kernel<<<32768, 256, 0, stream>>>(k_buf, gk);

  attn_simple_kernel<<<32, 256, 0, stream>>>(q_buf, k_buf, v_buf, o_buf);

  gemm_bt_kernel<1><<<dim3(4, 128), 256, 0, stream>>>(o_buf, w_proj, proj_b, 16384, 512, 512,
      x, nullptr, nullptr, nullptr, nullptr, x2);

  ln_kernel<0><<<16384, 256, 0, stream>>>(x2, ln2_w, ln2_b, nullptr, h_buf);

  gemm_bt_kernel<2><<<dim3(16, 128), 256, 0, stream>>>(h_buf, w_fc1, fc1_b, 16384, 2048, 512,
      nullptr, mid, nullptr, nullptr, nullptr, nullptr);

  gemm_bt_kernel<3><<<dim3(4, 128), 256, 0, stream>>>(mid, w_fc2, fc2_b, 16384, 512, 2048,
      x2, nullptr, nullptr, nullptr, nullptr, (float*)d_out);

  (void)in_sizes; (void)n_in; (void)out_size; (void)ws_size;
}

// Round 5
// 725.124 us; speedup vs baseline: 2.8898x; 2.8898x over previous
//
#include <hip/hip_runtime.h>
#include <math.h>

typedef unsigned short u16;
typedef __bf16 bf16x8 __attribute__((ext_vector_type(8)));
typedef float f32x4 __attribute__((ext_vector_type(4)));

#define DEVI static __device__ __forceinline__

DEVI float b2f(u16 u) { union { unsigned int i; float f; } w; w.i = ((unsigned int)u) << 16; return w.f; }
DEVI u16 f2b(float f) {
  union { float f; unsigned int i; } w; w.f = f;
  unsigned int r = (w.i + 0x7FFFu + ((w.i >> 16) & 1u)) >> 16;
  return (u16)r;
}

// ---------------- f32 -> bf16 weight conversion ----------------
__global__ void conv_f2b_kernel(const float* __restrict__ s, u16* __restrict__ d, int n) {
  int i = blockIdx.x * 256 + threadIdx.x;
  int st = gridDim.x * 256;
  for (; i < n; i += st) d[i] = f2b(s[i]);
}

// ---------------- LayerNorm (+optional rel_bias), f32 in -> bf16 out ----------------
template<int ADD_REL>
__global__ __launch_bounds__(256) void ln_kernel(
    const float* __restrict__ x, const float* __restrict__ w, const float* __restrict__ bb,
    const float* __restrict__ rel, u16* __restrict__ out) {
  int row = blockIdx.x;            // 0..16383 = b*4096 + l
  int t = threadIdx.x;             // 256
  const float* xr = x + (size_t)row * 512;
  float v0 = xr[t], v1 = xr[t + 256];
  float s = v0 + v1, ss = v0 * v0 + v1 * v1;
#pragma unroll
  for (int o = 32; o > 0; o >>= 1) { s += __shfl_down(s, o); ss += __shfl_down(ss, o); }
  __shared__ float rs[4], rss[4];
  int lane = t & 63, wid = t >> 6;
  if (lane == 0) { rs[wid] = s; rss[wid] = ss; }
  __syncthreads();
  s = rs[0] + rs[1] + rs[2] + rs[3];
  ss = rss[0] + rss[1] + rss[2] + rss[3];
  float mu = s * (1.0f / 512.0f);
  float inv = rsqrtf(ss * (1.0f / 512.0f) - mu * mu + 1e-5f);
  float o0 = (v0 - mu) * inv * w[t] + bb[t];
  float o1 = (v1 - mu) * inv * w[t + 256] + bb[t + 256];
  if (ADD_REL) {
    const float* rr = rel + (size_t)(row & 4095) * 512;
    o0 += rr[t]; o1 += rr[t + 256];
  }
  u16* orow = out + (size_t)row * 512;
  orow[t] = f2b(o0);
  orow[t + 256] = f2b(o1);
}

// ---------------- GEMM: C[M,N] = A[M,K] @ W[N,K]^T + bias, bf16 MFMA ----------------
// EPI: 0=qkv scatter, 1=proj+residual->f32, 2=gelu->bf16, 3=fc2+residual->f32 (d_out)
template<int EPI>
__global__ __launch_bounds__(256) void gemm_bt_kernel(
    const u16* __restrict__ A, const u16* __restrict__ W,
    const float* __restrict__ bias, int M, int N, int K,
    const float* __restrict__ resid, u16* __restrict__ outb,
    u16* __restrict__ q_out, u16* __restrict__ k_out, u16* __restrict__ v_out,
    float* __restrict__ outf) {
  constexpr int LDT = 40;                      // 32 + 8 pad (80B rows, 16B aligned)
  __shared__ u16 As[128 * LDT];
  __shared__ u16 Bs[128 * LDT];
  int bn = blockIdx.x, bm = blockIdx.y;
  int m0 = bm * 128, n0 = bn * 128;
  int t = threadIdx.x, lane = t & 63, wid = t >> 6;
  int wr = (wid >> 1) * 64, wc = (wid & 1) * 64;    // wave -> 64x64 quadrant
  int fr = lane & 15, fk = (lane >> 4) * 8;
  f32x4 acc[4][4] = {};
  for (int k0 = 0; k0 < K; k0 += 32) {
#pragma unroll
    for (int i = 0; i < 2; ++i) {               // stage 128x32 A and B tiles
      int seg = t + i * 256;
      int r = seg >> 2, c = (seg & 3) * 8;
      *(uint4*)&As[r * LDT + c] = *(const uint4*)&A[(size_t)(m0 + r) * K + k0 + c];
      *(uint4*)&Bs[r * LDT + c] = *(const uint4*)&W[(size_t)(n0 + r) * K + k0 + c];
    }
    __syncthreads();
    bf16x8 af[4], bfr[4];
#pragma unroll
    for (int i = 0; i < 4; ++i) af[i] = *(const bf16x8*)&As[(wr + i * 16 + fr) * LDT + fk];
#pragma unroll
    for (int j = 0; j < 4; ++j) bfr[j] = *(const bf16x8*)&Bs[(wc + j * 16 + fr) * LDT + fk];
#pragma unroll
    for (int i = 0; i < 4; ++i)
#pragma unroll
      for (int j = 0; j < 4; ++j)
        acc[i][j] = __builtin_amdgcn_mfma_f32_16x16x32_bf16(af[i], bfr[j], acc[i][j], 0, 0, 0);
    __syncthreads();
  }
  int fq = lane >> 4;
#pragma unroll
  for (int i = 0; i < 4; ++i) {
#pragma unroll
    for (int j = 0; j < 4; ++j) {
#pragma unroll
      for (int jj = 0; jj < 4; ++jj) {
        int gm = m0 + wr + i * 16 + fq * 4 + jj;
        int gn = n0 + wc + j * 16 + fr;
        float v = acc[i][j][jj] + bias[gn];
        if (EPI == 0) {
          // qkv: n -> (which, head, d); write (b,h,l,d) contiguous
          int which = gn >> 9, head = (gn >> 6) & 7, dd = gn & 63;
          int b = gm >> 12, l = gm & 4095;
          u16* dst = (which == 0) ? q_out : (which == 1) ? k_out : v_out;
          dst[(((size_t)(b * 8 + head) * 4096) + l) * 64 + dd] = f2b(v);
        } else if (EPI == 1) {
          size_t idx = (size_t)gm * 512 + gn;
          outf[idx] = v + resid[idx];
        } else if (EPI == 2) {
          float g = 0.5f * v * (1.0f + erff(v * 0.70710678118654752f));
          outb[(size_t)gm * (size_t)N + gn] = f2b(g);
        } else {
          size_t idx = (size_t)gm * 512 + gn;
          outf[idx] = v + resid[idx];               // f32 store to d_out
        }
      }
    }
  }
}

// ---------------- RMSNorm over HD=64, in-place on bf16 q/k ----------------
__global__ __launch_bounds__(256) void rms_kernel(u16* __restrict__ qk, const float* __restrict__ g) {
  int row = blockIdx.x * 4 + (threadIdx.x >> 6);   // (b*8+h)*4096 + l
  int d = threadIdx.x & 63;
  size_t idx = (size_t)row * 64 + d;
  float v = b2f(qk[idx]);
  float ss = v * v;
#pragma unroll
  for (int o = 32; o > 0; o >>= 1) ss += __shfl_xor(ss, o);
  float nrm = fmaxf(sqrtf(ss), 1e-12f);
  int head = (row >> 12) & 7;
  qk[idx] = f2b(v / nrm * 8.0f * g[head * 64 + d]);
}

// ---------------- Lightning attention, MFMA version: one block per (b,h) ----------------
__global__ __launch_bounds__(256) void attn_kernel(
    const u16* __restrict__ q, const u16* __restrict__ k, const u16* __restrict__ v,
    u16* __restrict__ o) {
  constexpr int LQ = 72, LT = 136, LS = 136, LKV = 72;
  __shared__ u16 q_s[128 * LQ], k_s[128 * LQ];     // row-major (l, d)
  __shared__ u16 kT_s[64 * LT], vT_s[64 * LT];     // transposed (d, l), kT pre-scaled by kdec
  __shared__ u16 S_s[128 * LS], kvT_s[64 * LKV];   // masked scores; kv transposed bf16
  __shared__ float kv_s[64 * 64];                  // running state, f32
  __shared__ float rowf[128], colf[128], kdec[128];
  int bh = blockIdx.x;
  float sl = exp2f(-(float)((bh & 7) + 1));        // slopes are exact powers of two
  int t = threadIdx.x, lane = t & 63, wid = t >> 6;
  for (int i = t; i < 128; i += 256) {
    rowf[i] = expf(-sl * i);                       // q_dec / Dintra row factor
    colf[i] = expf(sl * i);                        // Dintra col factor
    kdec[i] = expf(-sl * (128 - i));
  }
  for (int i = t; i < 4096; i += 256) kv_s[i] = 0.0f;
  float cdec = expf(-sl * 128.0f);
  const u16* qb = q + (size_t)bh * 4096 * 64;
  const u16* kb = k + (size_t)bh * 4096 * 64;
  const u16* vb = v + (size_t)bh * 4096 * 64;
  u16* ob = o + (size_t)bh * 4096 * 64;            // (b,h,l,d) contiguous == reshape(b,l,c)
  int fr = lane & 15, fk = (lane >> 4) * 8, fq = lane >> 4;
  __syncthreads();
  for (int c = 0; c < 32; ++c) {
    int l0 = c * 128;
    // phase 1: stage q,k row-major; kT (scaled), vT transposed; kv -> bf16 transposed
#pragma unroll
    for (int i = 0; i < 4; ++i) {
      int seg = t + i * 256;
      int r = seg >> 3, cc = (seg & 7) * 8;
      *(uint4*)&q_s[r * LQ + cc] = *(const uint4*)&qb[(size_t)(l0 + r) * 64 + cc];
      *(uint4*)&k_s[r * LQ + cc] = *(const uint4*)&kb[(size_t)(l0 + r) * 64 + cc];
    }
#pragma unroll
    for (int i = 0; i < 16; ++i) {
      int seg = t + i * 256;
      int j = seg >> 5, dd = (seg & 31) * 2;
      unsigned int kp = *(const unsigned int*)&kb[(size_t)(l0 + j) * 64 + dd];
      float kd = kdec[j];
      kT_s[dd * LT + j] = f2b(b2f((u16)(kp & 0xFFFFu)) * kd);
      kT_s[(dd + 1) * LT + j] = f2b(b2f((u16)(kp >> 16)) * kd);
      unsigned int vp = *(const unsigned int*)&vb[(size_t)(l0 + j) * 64 + dd];
      vT_s[dd * LT + j] = (u16)(vp & 0xFFFFu);
      vT_s[(dd + 1) * LT + j] = (u16)(vp >> 16);
    }
#pragma unroll
    for (int i = 0; i < 16; ++i) {
      int seg = t + i * 256;
      int dd = seg >> 6, e = seg & 63;
      kvT_s[e * LKV + dd] = f2b(kv_s[dd * 64 + e]);
    }
    __syncthreads();
    // S = Q K^T  (wave owns rows [wid*32, wid*32+32), all 128 cols)
    f32x4 accS[2][8] = {};
#pragma unroll
    for (int kk = 0; kk < 2; ++kk) {
      bf16x8 aq0 = *(const bf16x8*)&q_s[(wid * 32 + fr) * LQ + kk * 32 + fk];
      bf16x8 aq1 = *(const bf16x8*)&q_s[(wid * 32 + 16 + fr) * LQ + kk * 32 + fk];
#pragma unroll
      for (int j = 0; j < 8; ++j) {
        bf16x8 bk = *(const bf16x8*)&k_s[(j * 16 + fr) * LQ + kk * 32 + fk];
        accS[0][j] = __builtin_amdgcn_mfma_f32_16x16x32_bf16(aq0, bk, accS[0][j], 0, 0, 0);
        accS[1][j] = __builtin_amdgcn_mfma_f32_16x16x32_bf16(aq1, bk, accS[1][j], 0, 0, 0);
      }
    }
    // decay-mask and park S' in LDS as bf16 (same wave re-reads its own rows)
#pragma unroll
    for (int i = 0; i < 2; ++i)
#pragma unroll
      for (int j = 0; j < 8; ++j)
#pragma unroll
        for (int jj = 0; jj < 4; ++jj) {
          int si = wid * 32 + i * 16 + fq * 4 + jj;
          int sj = j * 16 + fr;
          float val = (si >= sj) ? accS[i][j][jj] * rowf[si] * colf[sj] : 0.0f;
          S_s[si * LS + sj] = f2b(val);
        }
    // inter = Q @ kv  (q_dec row scale applied at epilogue)
    f32x4 accI[2][4] = {};
#pragma unroll
    for (int kk = 0; kk < 2; ++kk) {
      bf16x8 aq0 = *(const bf16x8*)&q_s[(wid * 32 + fr) * LQ + kk * 32 + fk];
      bf16x8 aq1 = *(const bf16x8*)&q_s[(wid * 32 + 16 + fr) * LQ + kk * 32 + fk];
#pragma unroll
      for (int j = 0; j < 4; ++j) {
        bf16x8 bkv = *(const bf16x8*)&kvT_s[(j * 16 + fr) * LKV + kk * 32 + fk];
        accI[0][j] = __builtin_amdgcn_mfma_f32_16x16x32_bf16(aq0, bkv, accI[0][j], 0, 0, 0);
        accI[1][j] = __builtin_amdgcn_mfma_f32_16x16x32_bf16(aq1, bkv, accI[1][j], 0, 0, 0);
      }
    }
    // kv update accumulator: (k*kdec)^T @ v  (wave owns d-rows [wid*16, wid*16+16))
    f32x4 accKV[4] = {};
#pragma unroll
    for (int kk = 0; kk < 4; ++kk) {
      bf16x8 akt = *(const bf16x8*)&kT_s[(wid * 16 + fr) * LT + kk * 32 + fk];
#pragma unroll
      for (int j = 0; j < 4; ++j) {
        bf16x8 bvt = *(const bf16x8*)&vT_s[(j * 16 + fr) * LT + kk * 32 + fk];
        accKV[j] = __builtin_amdgcn_mfma_f32_16x16x32_bf16(akt, bvt, accKV[j], 0, 0, 0);
      }
    }
    // intra = S' @ V
    f32x4 accO[2][4] = {};
#pragma unroll
    for (int kk = 0; kk < 4; ++kk) {
      bf16x8 as0 = *(const bf16x8*)&S_s[(wid * 32 + fr) * LS + kk * 32 + fk];
      bf16x8 as1 = *(const bf16x8*)&S_s[(wid * 32 + 16 + fr) * LS + kk * 32 + fk];
#pragma unroll
      for (int j = 0; j < 4; ++j) {
        bf16x8 bvt = *(const bf16x8*)&vT_s[(j * 16 + fr) * LT + kk * 32 + fk];
        accO[0][j] = __builtin_amdgcn_mfma_f32_16x16x32_bf16(as0, bvt, accO[0][j], 0, 0, 0);
        accO[1][j] = __builtin_amdgcn_mfma_f32_16x16x32_bf16(as1, bvt, accO[1][j], 0, 0, 0);
      }
    }
    // epilogue: out = intra + q_dec[row]*inter ; kv = cdec*kv + accKV
#pragma unroll
    for (int i = 0; i < 2; ++i)
#pragma unroll
      for (int j = 0; j < 4; ++j)
#pragma unroll
        for (int jj = 0; jj < 4; ++jj) {
          int li = wid * 32 + i * 16 + fq * 4 + jj;
          int e = j * 16 + fr;
          float val = accO[i][j][jj] + rowf[li] * accI[i][j][jj];
          ob[(size_t)(l0 + li) * 64 + e] = f2b(val);
        }
#pragma unroll
    for (int j = 0; j < 4; ++j)
#pragma unroll
      for (int jj = 0; jj < 4; ++jj) {
        int dd = wid * 16 + fq * 4 + jj;
        int e = j * 16 + fr;
        kv_s[dd * 64 + e] = cdec * kv_s[dd * 64 + e] + accKV[j][jj];
      }
    __syncthreads();
  }
}

extern "C" void kernel_launch(void* const* d_in, const int* in_sizes, int n_in,
                              void* d_out, int out_size, void* d_ws, size_t ws_size,
                              hipStream_t stream) {
  // Inputs f32; output f32 (validated round 4).
  const float* x      = (const float*)d_in[0];
  const float* ln1_w  = (const float*)d_in[1];
  const float* ln1_b  = (const float*)d_in[2];
  const float* rel    = (const float*)d_in[3];
  const float* qkv_w  = (const float*)d_in[4];
  const float* qkv_b  = (const float*)d_in[5];
  const float* gq     = (const float*)d_in[6];
  const float* gk     = (const float*)d_in[7];
  const float* proj_w = (const float*)d_in[8];
  const float* proj_b = (const float*)d_in[9];
  const float* ln2_w  = (const float*)d_in[10];
  const float* ln2_b  = (const float*)d_in[11];
  const float* fc1_w  = (const float*)d_in[12];
  const float* fc1_b  = (const float*)d_in[13];
  const float* fc2_w  = (const float*)d_in[14];
  const float* fc2_b  = (const float*)d_in[15];

  char* ws = (char*)d_ws;
  size_t off = 0;
  auto alloc = [&](size_t bytes) { char* p = ws + off; off += (bytes + 255) & ~(size_t)255; return p; };
  u16* w_qkv  = (u16*)alloc((size_t)1536 * 512 * 2);
  u16* w_proj = (u16*)alloc((size_t)512 * 512 * 2);
  u16* w_fc1  = (u16*)alloc((size_t)2048 * 512 * 2);
  u16* w_fc2  = (u16*)alloc((size_t)512 * 2048 * 2);
  u16* h_buf  = (u16*)alloc((size_t)16384 * 512 * 2);   // ln1 out; reused for ln2 out
  u16* q_buf  = (u16*)alloc((size_t)8388608 * 2);
  u16* k_buf  = (u16*)alloc((size_t)8388608 * 2);
  u16* v_buf  = (u16*)alloc((size_t)8388608 * 2);
  u16* o_buf  = (u16*)alloc((size_t)8388608 * 2);
  float* x2   = (float*)alloc((size_t)8388608 * 4);
  u16* mid    = q_buf;   // 16384x2048 bf16 overlays q..o (dead after attention/proj)

  conv_f2b_kernel<<<512, 256, 0, stream>>>(qkv_w, w_qkv, 1536 * 512);
  conv_f2b_kernel<<<512, 256, 0, stream>>>(proj_w, w_proj, 512 * 512);
  conv_f2b_kernel<<<512, 256, 0, stream>>>(fc1_w, w_fc1, 2048 * 512);
  conv_f2b_kernel<<<512, 256, 0, stream>>>(fc2_w, w_fc2, 512 * 2048);

  ln_kernel<1><<<16384, 256, 0, stream>>>(x, ln1_w, ln1_b, rel, h_buf);

  gemm_bt_kernel<0><<<dim3(12, 128), 256, 0, stream>>>(h_buf, w_qkv, qkv_b, 16384, 1536, 512,
      nullptr, nullptr, q_buf, k_buf, v_buf, nullptr);

  rms_kernel<<<32768, 256, 0, stream>>>(q_buf, gq);
  rms_kernel<<<32768, 256, 0, stream>>>(k_buf, gk);

  attn_kernel<<<32, 256, 0, stream>>>(q_buf, k_buf, v_buf, o_buf);

  gemm_bt_kernel<1><<<dim3(4, 128), 256, 0, stream>>>(o_buf, w_proj, proj_b, 16384, 512, 512,
      x, nullptr, nullptr, nullptr, nullptr, x2);

  ln_kernel<0><<<16384, 256, 0, stream>>>(x2, ln2_w, ln2_b, nullptr, h_buf);

  gemm_bt_kernel<2><<<dim3(16, 128), 256, 0, stream>>>(h_buf, w_fc1, fc1_b, 16384, 2048, 512,
      nullptr, mid, nullptr, nullptr, nullptr, nullptr);

  gemm_bt_kernel<3><<<dim3(4, 128), 256, 0, stream>>>(mid, w_fc2, fc2_b, 16384, 512, 2048,
      x2, nullptr, nullptr, nullptr, nullptr, (float*)d_out);

  (void)in_sizes; (void)n_in; (void)out_size; (void)ws_size;
}

// Round 6
// 357.006 us; speedup vs baseline: 5.8696x; 2.0311x over previous
//
#include <hip/hip_runtime.h>
#include <math.h>

typedef unsigned short u16;
typedef __bf16 bf16x8 __attribute__((ext_vector_type(8)));
typedef float f32x4 __attribute__((ext_vector_type(4)));

#define DEVI static __device__ __forceinline__

DEVI float b2f(u16 u) { union { unsigned int i; float f; } w; w.i = ((unsigned int)u) << 16; return w.f; }
DEVI u16 f2b(float f) {
  union { float f; unsigned int i; } w; w.f = f;
  unsigned int r = (w.i + 0x7FFFu + ((w.i >> 16) & 1u)) >> 16;
  return (u16)r;
}

// ---------------- f32 -> bf16 weight conversion ----------------
__global__ void conv_f2b_kernel(const float* __restrict__ s, u16* __restrict__ d, int n) {
  int i = blockIdx.x * 256 + threadIdx.x;
  int st = gridDim.x * 256;
  for (; i < n; i += st) d[i] = f2b(s[i]);
}

// ---------------- LayerNorm (+optional rel_bias), f32 in -> bf16 out ----------------
template<int ADD_REL>
__global__ __launch_bounds__(256) void ln_kernel(
    const float* __restrict__ x, const float* __restrict__ w, const float* __restrict__ bb,
    const float* __restrict__ rel, u16* __restrict__ out) {
  int row = blockIdx.x;            // 0..16383 = b*4096 + l
  int t = threadIdx.x;             // 256
  const float* xr = x + (size_t)row * 512;
  float v0 = xr[t], v1 = xr[t + 256];
  float s = v0 + v1, ss = v0 * v0 + v1 * v1;
#pragma unroll
  for (int o = 32; o > 0; o >>= 1) { s += __shfl_down(s, o); ss += __shfl_down(ss, o); }
  __shared__ float rs[4], rss[4];
  int lane = t & 63, wid = t >> 6;
  if (lane == 0) { rs[wid] = s; rss[wid] = ss; }
  __syncthreads();
  s = rs[0] + rs[1] + rs[2] + rs[3];
  ss = rss[0] + rss[1] + rss[2] + rss[3];
  float mu = s * (1.0f / 512.0f);
  float inv = rsqrtf(ss * (1.0f / 512.0f) - mu * mu + 1e-5f);
  float o0 = (v0 - mu) * inv * w[t] + bb[t];
  float o1 = (v1 - mu) * inv * w[t + 256] + bb[t + 256];
  if (ADD_REL) {
    const float* rr = rel + (size_t)(row & 4095) * 512;
    o0 += rr[t]; o1 += rr[t + 256];
  }
  u16* orow = out + (size_t)row * 512;
  orow[t] = f2b(o0);
  orow[t + 256] = f2b(o1);
}

// ---------------- GEMM: C[M,N] = A[M,K] @ W[N,K]^T + bias, bf16 MFMA ----------------
// EPI: 0=qkv scatter, 1=proj+residual->f32, 2=gelu->bf16, 3=fc2+residual->f32 (d_out)
template<int EPI>
__global__ __launch_bounds__(256) void gemm_bt_kernel(
    const u16* __restrict__ A, const u16* __restrict__ W,
    const float* __restrict__ bias, int M, int N, int K,
    const float* __restrict__ resid, u16* __restrict__ outb,
    u16* __restrict__ q_out, u16* __restrict__ k_out, u16* __restrict__ v_out,
    float* __restrict__ outf) {
  constexpr int LDT = 40;                      // 32 + 8 pad (80B rows, 16B aligned)
  __shared__ u16 As[128 * LDT];
  __shared__ u16 Bs[128 * LDT];
  int bn = blockIdx.x, bm = blockIdx.y;
  int m0 = bm * 128, n0 = bn * 128;
  int t = threadIdx.x, lane = t & 63, wid = t >> 6;
  int wr = (wid >> 1) * 64, wc = (wid & 1) * 64;    // wave -> 64x64 quadrant
  int fr = lane & 15, fk = (lane >> 4) * 8;
  f32x4 acc[4][4] = {};
  for (int k0 = 0; k0 < K; k0 += 32) {
#pragma unroll
    for (int i = 0; i < 2; ++i) {               // stage 128x32 A and B tiles
      int seg = t + i * 256;
      int r = seg >> 2, c = (seg & 3) * 8;
      *(uint4*)&As[r * LDT + c] = *(const uint4*)&A[(size_t)(m0 + r) * K + k0 + c];
      *(uint4*)&Bs[r * LDT + c] = *(const uint4*)&W[(size_t)(n0 + r) * K + k0 + c];
    }
    __syncthreads();
    bf16x8 af[4], bfr[4];
#pragma unroll
    for (int i = 0; i < 4; ++i) af[i] = *(const bf16x8*)&As[(wr + i * 16 + fr) * LDT + fk];
#pragma unroll
    for (int j = 0; j < 4; ++j) bfr[j] = *(const bf16x8*)&Bs[(wc + j * 16 + fr) * LDT + fk];
#pragma unroll
    for (int i = 0; i < 4; ++i)
#pragma unroll
      for (int j = 0; j < 4; ++j)
        acc[i][j] = __builtin_amdgcn_mfma_f32_16x16x32_bf16(af[i], bfr[j], acc[i][j], 0, 0, 0);
    __syncthreads();
  }
  int fq = lane >> 4;
#pragma unroll
  for (int i = 0; i < 4; ++i) {
#pragma unroll
    for (int j = 0; j < 4; ++j) {
#pragma unroll
      for (int jj = 0; jj < 4; ++jj) {
        int gm = m0 + wr + i * 16 + fq * 4 + jj;
        int gn = n0 + wc + j * 16 + fr;
        float v = acc[i][j][jj] + bias[gn];
        if (EPI == 0) {
          // qkv: n -> (which, head, d); write (b,h,l,d) contiguous
          int which = gn >> 9, head = (gn >> 6) & 7, dd = gn & 63;
          int b = gm >> 12, l = gm & 4095;
          u16* dst = (which == 0) ? q_out : (which == 1) ? k_out : v_out;
          dst[(((size_t)(b * 8 + head) * 4096) + l) * 64 + dd] = f2b(v);
        } else if (EPI == 1) {
          size_t idx = (size_t)gm * 512 + gn;
          outf[idx] = v + resid[idx];
        } else if (EPI == 2) {
          float g = 0.5f * v * (1.0f + erff(v * 0.70710678118654752f));
          outb[(size_t)gm * (size_t)N + gn] = f2b(g);
        } else {
          size_t idx = (size_t)gm * 512 + gn;
          outf[idx] = v + resid[idx];               // f32 store to d_out
        }
      }
    }
  }
}

// ---------------- RMSNorm over HD=64, in-place on bf16 q/k ----------------
__global__ __launch_bounds__(256) void rms_kernel(u16* __restrict__ qk, const float* __restrict__ g) {
  int row = blockIdx.x * 4 + (threadIdx.x >> 6);   // (b*8+h)*4096 + l
  int d = threadIdx.x & 63;
  size_t idx = (size_t)row * 64 + d;
  float v = b2f(qk[idx]);
  float ss = v * v;
#pragma unroll
  for (int o = 32; o > 0; o >>= 1) ss += __shfl_xor(ss, o);
  float nrm = fmaxf(sqrtf(ss), 1e-12f);
  int head = (row >> 12) & 7;
  qk[idx] = f2b(v / nrm * 8.0f * g[head * 64 + d]);
}

// ---------------- Attention pass 1: per-chunk kv partial P_c = (k*kdec)^T @ v ----------------
// grid 1024 = bh*32 + c. Output P[bid] as f32 64x64 in (e, dd) layout.
__global__ __launch_bounds__(256) void attn_kv_kernel(
    const u16* __restrict__ k, const u16* __restrict__ v, float* __restrict__ P) {
  constexpr int LT = 136;
  __shared__ __align__(16) u16 kT_s[64 * LT];
  __shared__ __align__(16) u16 vT_s[64 * LT];
  __shared__ float kdec[128];
  int bid = blockIdx.x;
  int bh = bid >> 5;
  float sl = exp2f(-(float)((bh & 7) + 1));
  int t = threadIdx.x, lane = t & 63, wid = t >> 6;
  for (int i = t; i < 128; i += 256) kdec[i] = expf(-sl * (float)(128 - i));
  const u16* kb = k + (size_t)bid * 8192;
  const u16* vb = v + (size_t)bid * 8192;
  __syncthreads();
  int fr = lane & 15, fk = (lane >> 4) * 8, fq = lane >> 4;
#pragma unroll
  for (int i = 0; i < 16; ++i) {
    int seg = t + i * 256;
    int j = seg >> 5, dd = (seg & 31) * 2;
    unsigned int kp = *(const unsigned int*)&kb[(size_t)j * 64 + dd];
    float kd = kdec[j];
    kT_s[dd * LT + j] = f2b(b2f((u16)(kp & 0xFFFFu)) * kd);
    kT_s[(dd + 1) * LT + j] = f2b(b2f((u16)(kp >> 16)) * kd);
    unsigned int vp = *(const unsigned int*)&vb[(size_t)j * 64 + dd];
    vT_s[dd * LT + j] = (u16)(vp & 0xFFFFu);
    vT_s[(dd + 1) * LT + j] = (u16)(vp >> 16);
  }
  __syncthreads();
  f32x4 accKV[4] = {};
#pragma unroll
  for (int kk = 0; kk < 4; ++kk) {
    bf16x8 akt = *(const bf16x8*)&kT_s[(wid * 16 + fr) * LT + kk * 32 + fk];
#pragma unroll
    for (int j = 0; j < 4; ++j) {
      bf16x8 bvt = *(const bf16x8*)&vT_s[(j * 16 + fr) * LT + kk * 32 + fk];
      accKV[j] = __builtin_amdgcn_mfma_f32_16x16x32_bf16(akt, bvt, accKV[j], 0, 0, 0);
    }
  }
  // park P^T (e, dd) into f32 LDS (overlay kT_s), stride 68 to spread banks
  float* PT = (float*)kT_s;      // 64*68*4 = 17408 B <= kT_s 34816 B
  __syncthreads();
#pragma unroll
  for (int j = 0; j < 4; ++j)
#pragma unroll
    for (int jj = 0; jj < 4; ++jj) {
      int dd = wid * 16 + fq * 4 + jj;
      int e = j * 16 + fr;
      PT[e * 68 + dd] = accKV[j][jj];
    }
  __syncthreads();
  float* Pg = P + (size_t)bid * 4096;
  int e = t >> 2, d0 = (t & 3) * 16;
#pragma unroll
  for (int g = 0; g < 4; ++g) {
    f32x4 val = *(const f32x4*)&PT[e * 68 + d0 + g * 4];
    *(f32x4*)&Pg[(size_t)e * 64 + d0 + g * 4] = val;
  }
}

// ---------------- Attention pass 2: scan kv state; emit pre-chunk state as bf16 (e,d) ----------------
// grid 32 = bh. Thread t owns flat elements [t*16, t*16+16) of the (e,d) 64x64 state.
__global__ __launch_bounds__(256) void attn_scan_kernel(
    const float* __restrict__ P, u16* __restrict__ kvst) {
  int bh = blockIdx.x, t = threadIdx.x;
  float sl = exp2f(-(float)((bh & 7) + 1));
  float cdec = expf(-sl * 128.0f);
  float kv[16];
#pragma unroll
  for (int i = 0; i < 16; ++i) kv[i] = 0.f;
  for (int c = 0; c < 32; ++c) {
    size_t off = (((size_t)bh * 32 + c) * 4096) + (size_t)t * 16;
    union { u16 st[16]; uint4 v4[4]; } u;
#pragma unroll
    for (int i = 0; i < 16; ++i) u.st[i] = f2b(kv[i]);
    *(uint4*)&kvst[off] = u.v4[0];
    *(uint4*)&kvst[off + 8] = u.v4[1];
#pragma unroll
    for (int g = 0; g < 4; ++g) {
      f32x4 p = *(const f32x4*)&P[off + g * 4];
#pragma unroll
      for (int e = 0; e < 4; ++e) kv[g * 4 + e] = cdec * kv[g * 4 + e] + p[e];
    }
  }
}

// ---------------- Attention pass 3: out_c = masked(QK^T)@V + qdec*(Q@kv_state) ----------------
// grid 1024 = bh*32 + c. LDS 63.5KB -> 2 blocks/CU.
__global__ __launch_bounds__(256) void attn_out_kernel(
    const u16* __restrict__ q, const u16* __restrict__ k, const u16* __restrict__ v,
    const u16* __restrict__ kvst, u16* __restrict__ o) {
  constexpr int LQ = 72, LT = 136, LS = 136, LKV = 72;
  __shared__ __align__(16) u16 sm[31744];
  u16* q_s  = sm;              // 128*72
  u16* k_s  = sm + 9216;       // 128*72
  u16* vT_s = sm + 18432;      // 64*136
  u16* kvT_s = sm + 27136;     // 64*72
  u16* S_s  = sm;              // 128*136 overlays q_s+k_s (dead after S/inter MFMA)
  __shared__ float rowf[128], colf[128];
  int bid = blockIdx.x;
  int bh = bid >> 5;
  float sl = exp2f(-(float)((bh & 7) + 1));
  int t = threadIdx.x, lane = t & 63, wid = t >> 6;
  for (int i = t; i < 128; i += 256) {
    rowf[i] = expf(-sl * i);
    colf[i] = expf(sl * i);
  }
  const u16* qb = q + (size_t)bid * 8192;
  const u16* kb = k + (size_t)bid * 8192;
  const u16* vb = v + (size_t)bid * 8192;
  const u16* kvb = kvst + (size_t)bid * 4096;
  u16* ob = o + (size_t)bid * 8192;
  int fr = lane & 15, fk = (lane >> 4) * 8, fq = lane >> 4;
#pragma unroll
  for (int i = 0; i < 4; ++i) {        // q,k row-major
    int seg = t + i * 256;
    int r = seg >> 3, cc = (seg & 7) * 8;
    *(uint4*)&q_s[r * LQ + cc] = *(const uint4*)&qb[(size_t)r * 64 + cc];
    *(uint4*)&k_s[r * LQ + cc] = *(const uint4*)&kb[(size_t)r * 64 + cc];
  }
#pragma unroll
  for (int i = 0; i < 16; ++i) {       // vT transpose
    int seg = t + i * 256;
    int j = seg >> 5, dd = (seg & 31) * 2;
    unsigned int vp = *(const unsigned int*)&vb[(size_t)j * 64 + dd];
    vT_s[dd * LT + j] = (u16)(vp & 0xFFFFu);
    vT_s[(dd + 1) * LT + j] = (u16)(vp >> 16);
  }
#pragma unroll
  for (int i = 0; i < 2; ++i) {        // kv state straight copy (already (e,d))
    int seg = t + i * 256;
    int e = seg >> 3, dd = (seg & 7) * 8;
    *(uint4*)&kvT_s[e * LKV + dd] = *(const uint4*)&kvb[(size_t)e * 64 + dd];
  }
  __syncthreads();
  // S = Q K^T and inter = Q @ kv  (wave owns q-rows [wid*32, +32))
  f32x4 accS[2][8] = {};
  f32x4 accI[2][4] = {};
#pragma unroll
  for (int kk = 0; kk < 2; ++kk) {
    bf16x8 aq0 = *(const bf16x8*)&q_s[(wid * 32 + fr) * LQ + kk * 32 + fk];
    bf16x8 aq1 = *(const bf16x8*)&q_s[(wid * 32 + 16 + fr) * LQ + kk * 32 + fk];
#pragma unroll
    for (int j = 0; j < 8; ++j) {
      bf16x8 bk = *(const bf16x8*)&k_s[(j * 16 + fr) * LQ + kk * 32 + fk];
      accS[0][j] = __builtin_amdgcn_mfma_f32_16x16x32_bf16(aq0, bk, accS[0][j], 0, 0, 0);
      accS[1][j] = __builtin_amdgcn_mfma_f32_16x16x32_bf16(aq1, bk, accS[1][j], 0, 0, 0);
    }
#pragma unroll
    for (int j = 0; j < 4; ++j) {
      bf16x8 bkv = *(const bf16x8*)&kvT_s[(j * 16 + fr) * LKV + kk * 32 + fk];
      accI[0][j] = __builtin_amdgcn_mfma_f32_16x16x32_bf16(aq0, bkv, accI[0][j], 0, 0, 0);
      accI[1][j] = __builtin_amdgcn_mfma_f32_16x16x32_bf16(aq1, bkv, accI[1][j], 0, 0, 0);
    }
  }
  __syncthreads();   // q_s,k_s now dead -> S_s region reusable
#pragma unroll
  for (int i = 0; i < 2; ++i)
#pragma unroll
    for (int j = 0; j < 8; ++j)
#pragma unroll
      for (int jj = 0; jj < 4; ++jj) {
        int si = wid * 32 + i * 16 + fq * 4 + jj;
        int sj = j * 16 + fr;
        float val = (si >= sj) ? accS[i][j][jj] * rowf[si] * colf[sj] : 0.0f;
        S_s[si * LS + sj] = f2b(val);
      }
  __syncthreads();
  // intra = S' @ V
  f32x4 accO[2][4] = {};
#pragma unroll
  for (int kk = 0; kk < 4; ++kk) {
    bf16x8 as0 = *(const bf16x8*)&S_s[(wid * 32 + fr) * LS + kk * 32 + fk];
    bf16x8 as1 = *(const bf16x8*)&S_s[(wid * 32 + 16 + fr) * LS + kk * 32 + fk];
#pragma unroll
    for (int j = 0; j < 4; ++j) {
      bf16x8 bvt = *(const bf16x8*)&vT_s[(j * 16 + fr) * LT + kk * 32 + fk];
      accO[0][j] = __builtin_amdgcn_mfma_f32_16x16x32_bf16(as0, bvt, accO[0][j], 0, 0, 0);
      accO[1][j] = __builtin_amdgcn_mfma_f32_16x16x32_bf16(as1, bvt, accO[1][j], 0, 0, 0);
    }
  }
#pragma unroll
  for (int i = 0; i < 2; ++i)
#pragma unroll
    for (int j = 0; j < 4; ++j)
#pragma unroll
      for (int jj = 0; jj < 4; ++jj) {
        int li = wid * 32 + i * 16 + fq * 4 + jj;
        int e = j * 16 + fr;
        float val = accO[i][j][jj] + rowf[li] * accI[i][j][jj];
        ob[(size_t)li * 64 + e] = f2b(val);
      }
}

extern "C" void kernel_launch(void* const* d_in, const int* in_sizes, int n_in,
                              void* d_out, int out_size, void* d_ws, size_t ws_size,
                              hipStream_t stream) {
  // Inputs f32; output f32 (validated round 4).
  const float* x      = (const float*)d_in[0];
  const float* ln1_w  = (const float*)d_in[1];
  const float* ln1_b  = (const float*)d_in[2];
  const float* rel    = (const float*)d_in[3];
  const float* qkv_w  = (const float*)d_in[4];
  const float* qkv_b  = (const float*)d_in[5];
  const float* gq     = (const float*)d_in[6];
  const float* gk     = (const float*)d_in[7];
  const float* proj_w = (const float*)d_in[8];
  const float* proj_b = (const float*)d_in[9];
  const float* ln2_w  = (const float*)d_in[10];
  const float* ln2_b  = (const float*)d_in[11];
  const float* fc1_w  = (const float*)d_in[12];
  const float* fc1_b  = (const float*)d_in[13];
  const float* fc2_w  = (const float*)d_in[14];
  const float* fc2_b  = (const float*)d_in[15];

  char* ws = (char*)d_ws;
  size_t off = 0;
  auto alloc = [&](size_t bytes) { char* p = ws + off; off += (bytes + 255) & ~(size_t)255; return p; };
  u16* w_qkv  = (u16*)alloc((size_t)1536 * 512 * 2);
  u16* w_proj = (u16*)alloc((size_t)512 * 512 * 2);
  u16* w_fc1  = (u16*)alloc((size_t)2048 * 512 * 2);
  u16* w_fc2  = (u16*)alloc((size_t)512 * 2048 * 2);
  u16* h_buf  = (u16*)alloc((size_t)16384 * 512 * 2);   // ln1 out; reused for ln2 out
  u16* q_buf  = (u16*)alloc((size_t)8388608 * 2);
  u16* k_buf  = (u16*)alloc((size_t)8388608 * 2);
  u16* v_buf  = (u16*)alloc((size_t)8388608 * 2);
  u16* o_buf  = (u16*)alloc((size_t)8388608 * 2);
  float* x2   = (float*)alloc((size_t)8388608 * 4);
  u16* mid    = q_buf;   // 16384x2048 bf16 overlays q..o (dead after attention/proj)
  // attention scratch overlays x2 (x2 written only after attention):
  float* P_glob  = x2;                       // 1024*4096 f32 = 16.8 MB
  u16*   kv_state = (u16*)(x2 + 4194304);    // 1024*4096 bf16 = 8.4 MB

  conv_f2b_kernel<<<512, 256, 0, stream>>>(qkv_w, w_qkv, 1536 * 512);
  conv_f2b_kernel<<<512, 256, 0, stream>>>(proj_w, w_proj, 512 * 512);
  conv_f2b_kernel<<<512, 256, 0, stream>>>(fc1_w, w_fc1, 2048 * 512);
  conv_f2b_kernel<<<512, 256, 0, stream>>>(fc2_w, w_fc2, 512 * 2048);

  ln_kernel<1><<<16384, 256, 0, stream>>>(x, ln1_w, ln1_b, rel, h_buf);

  gemm_bt_kernel<0><<<dim3(12, 128), 256, 0, stream>>>(h_buf, w_qkv, qkv_b, 16384, 1536, 512,
      nullptr, nullptr, q_buf, k_buf, v_buf, nullptr);

  rms_kernel<<<32768, 256, 0, stream>>>(q_buf, gq);
  rms_kernel<<<32768, 256, 0, stream>>>(k_buf, gk);

  attn_kv_kernel<<<1024, 256, 0, stream>>>(k_buf, v_buf, P_glob);
  attn_scan_kernel<<<32, 256, 0, stream>>>(P_glob, kv_state);
  attn_out_kernel<<<1024, 256, 0, stream>>>(q_buf, k_buf, v_buf, kv_state, o_buf);

  gemm_bt_kernel<1><<<dim3(4, 128), 256, 0, stream>>>(o_buf, w_proj, proj_b, 16384, 512, 512,
      x, nullptr, nullptr, nullptr, nullptr, x2);

  ln_kernel<0><<<16384, 256, 0, stream>>>(x2, ln2_w, ln2_b, nullptr, h_buf);

  gemm_bt_kernel<2><<<dim3(16, 128), 256, 0, stream>>>(h_buf, w_fc1, fc1_b, 16384, 2048, 512,
      nullptr, mid, nullptr, nullptr, nullptr, nullptr);

  gemm_bt_kernel<3><<<dim3(4, 128), 256, 0, stream>>>(mid, w_fc2, fc2_b, 16384, 512, 2048,
      x2, nullptr, nullptr, nullptr, nullptr, (float*)d_out);

  (void)in_sizes; (void)n_in; (void)out_size; (void)ws_size;
}

// Round 7
// 333.068 us; speedup vs baseline: 6.2914x; 1.0719x over previous
//
#include <hip/hip_runtime.h>
#include <math.h>

typedef unsigned short u16;
typedef __bf16 bf16x8 __attribute__((ext_vector_type(8)));
typedef float f32x4 __attribute__((ext_vector_type(4)));

#define DEVI static __device__ __forceinline__

DEVI float b2f(u16 u) { union { unsigned int i; float f; } w; w.i = ((unsigned int)u) << 16; return w.f; }
DEVI u16 f2b(float f) {
  union { float f; unsigned int i; } w; w.f = f;
  unsigned int r = (w.i + 0x7FFFu + ((w.i >> 16) & 1u)) >> 16;
  return (u16)r;
}

// ---------------- f32 -> bf16 weight conversion ----------------
__global__ void conv_f2b_kernel(const float* __restrict__ s, u16* __restrict__ d, int n) {
  int i = blockIdx.x * 256 + threadIdx.x;
  int st = gridDim.x * 256;
  for (; i < n; i += st) d[i] = f2b(s[i]);
}

// ---------------- LayerNorm (+optional rel_bias), f32 in -> bf16 out ----------------
template<int ADD_REL>
__global__ __launch_bounds__(256) void ln_kernel(
    const float* __restrict__ x, const float* __restrict__ w, const float* __restrict__ bb,
    const float* __restrict__ rel, u16* __restrict__ out) {
  int row = blockIdx.x;            // 0..16383 = b*4096 + l
  int t = threadIdx.x;             // 256
  const float* xr = x + (size_t)row * 512;
  float v0 = xr[t], v1 = xr[t + 256];
  float s = v0 + v1, ss = v0 * v0 + v1 * v1;
#pragma unroll
  for (int o = 32; o > 0; o >>= 1) { s += __shfl_down(s, o); ss += __shfl_down(ss, o); }
  __shared__ float rs[4], rss[4];
  int lane = t & 63, wid = t >> 6;
  if (lane == 0) { rs[wid] = s; rss[wid] = ss; }
  __syncthreads();
  s = rs[0] + rs[1] + rs[2] + rs[3];
  ss = rss[0] + rss[1] + rss[2] + rss[3];
  float mu = s * (1.0f / 512.0f);
  float inv = rsqrtf(ss * (1.0f / 512.0f) - mu * mu + 1e-5f);
  float o0 = (v0 - mu) * inv * w[t] + bb[t];
  float o1 = (v1 - mu) * inv * w[t + 256] + bb[t + 256];
  if (ADD_REL) {
    const float* rr = rel + (size_t)(row & 4095) * 512;
    o0 += rr[t]; o1 += rr[t + 256];
  }
  u16* orow = out + (size_t)row * 512;
  orow[t] = f2b(o0);
  orow[t + 256] = f2b(o1);
}

// ---------------- GEMM: C[M,N] = A[M,K] @ W[N,K]^T + bias, bf16 MFMA ----------------
// m97 structure: global_load_lds(16B) staging into LINEAR [128][32] LDS, 2 barriers/K-step.
// EPI: 0=qkv scatter + fused RMS on q/k, 1=proj+residual->f32, 2=gelu->bf16, 3=fc2+residual->f32
template<int EPI>
__global__ __launch_bounds__(256) void gemm_bt_kernel(
    const u16* __restrict__ A, const u16* __restrict__ W,
    const float* __restrict__ bias, int M, int N, int K,
    const float* __restrict__ resid, u16* __restrict__ outb,
    u16* __restrict__ q_out, u16* __restrict__ k_out, u16* __restrict__ v_out,
    float* __restrict__ outf, const float* __restrict__ gq, const float* __restrict__ gk) {
  __shared__ u16 As[128 * 32];                 // linear, no pad (global_load_lds dest)
  __shared__ u16 Bs[128 * 32];
  int bn = blockIdx.x, bm = blockIdx.y;
  int m0 = bm * 128, n0 = bn * 128;
  int t = threadIdx.x, lane = t & 63, wid = t >> 6;
  int wr = (wid >> 1) * 64, wc = (wid & 1) * 64;    // wave -> 64x64 quadrant
  int fr = lane & 15, fk = (lane >> 4) * 8;
  // staging addresses: wave wid stages rows [wid*32, wid*32+32) of both tiles.
  // chunk = 16 rows = 1KB; lane i covers row (i>>2), col (i&3)*8.
  int srow = wid * 32 + (lane >> 2);
  int scol = (lane & 3) * 8;
  const u16* gA = A + (size_t)(m0 + srow) * K + scol;
  const u16* gB = W + (size_t)(n0 + srow) * K + scol;
  u16* lA = &As[wid * 1024];                   // wave-uniform LDS base
  u16* lB = &Bs[wid * 1024];
  f32x4 acc[4][4] = {};
  for (int k0 = 0; k0 < K; k0 += 32) {
    __builtin_amdgcn_global_load_lds(gA + k0,          lA,       16, 0, 0);
    __builtin_amdgcn_global_load_lds(gA + k0 + 16 * K, lA + 512, 16, 0, 0);
    __builtin_amdgcn_global_load_lds(gB + k0,          lB,       16, 0, 0);
    __builtin_amdgcn_global_load_lds(gB + k0 + 16 * K, lB + 512, 16, 0, 0);
    __syncthreads();
    bf16x8 af[4], bfr[4];
#pragma unroll
    for (int i = 0; i < 4; ++i) af[i] = *(const bf16x8*)&As[(wr + i * 16 + fr) * 32 + fk];
#pragma unroll
    for (int j = 0; j < 4; ++j) bfr[j] = *(const bf16x8*)&Bs[(wc + j * 16 + fr) * 32 + fk];
#pragma unroll
    for (int i = 0; i < 4; ++i)
#pragma unroll
      for (int j = 0; j < 4; ++j)
        acc[i][j] = __builtin_amdgcn_mfma_f32_16x16x32_bf16(af[i], bfr[j], acc[i][j], 0, 0, 0);
    __syncthreads();
  }
  int fq = lane >> 4;
  if (EPI == 0) {
    // quadrant base is 64-aligned -> covers exactly one (which, head) d-range
    int nb = n0 + wc;
    int which = nb >> 9, head = (nb >> 6) & 7;
    const float* gg = (which == 0) ? gq : gk;
#pragma unroll
    for (int i = 0; i < 4; ++i) {
#pragma unroll
      for (int jj = 0; jj < 4; ++jj) {
        int gm = m0 + wr + i * 16 + fq * 4 + jj;
        int b = gm >> 12, l = gm & 4095;
        float v[4]; float ssum = 0.f;
#pragma unroll
        for (int j = 0; j < 4; ++j) {
          v[j] = acc[i][j][jj] + bias[nb + j * 16 + fr];
          ssum += v[j] * v[j];
        }
        u16* dst = (which == 0) ? q_out : (which == 1) ? k_out : v_out;
        size_t rowbase = (((size_t)(b * 8 + head) * 4096) + l) * 64;
        if (which == 2) {
#pragma unroll
          for (int j = 0; j < 4; ++j) dst[rowbase + j * 16 + fr] = f2b(v[j]);
        } else {
          // fused RMSNorm over the row's 64 d-values (4 regs x 16 fr-lanes)
#pragma unroll
          for (int o = 1; o < 16; o <<= 1) ssum += __shfl_xor(ssum, o);
          float inv = 8.0f / fmaxf(sqrtf(ssum), 1e-12f);
#pragma unroll
          for (int j = 0; j < 4; ++j)
            dst[rowbase + j * 16 + fr] = f2b(v[j] * inv * gg[head * 64 + j * 16 + fr]);
        }
      }
    }
  } else {
#pragma unroll
    for (int i = 0; i < 4; ++i) {
#pragma unroll
      for (int j = 0; j < 4; ++j) {
#pragma unroll
        for (int jj = 0; jj < 4; ++jj) {
          int gm = m0 + wr + i * 16 + fq * 4 + jj;
          int gn = n0 + wc + j * 16 + fr;
          float v = acc[i][j][jj] + bias[gn];
          if (EPI == 1) {
            size_t idx = (size_t)gm * 512 + gn;
            outf[idx] = v + resid[idx];
          } else if (EPI == 2) {
            float g = 0.5f * v * (1.0f + erff(v * 0.70710678118654752f));
            outb[(size_t)gm * (size_t)N + gn] = f2b(g);
          } else {
            size_t idx = (size_t)gm * 512 + gn;
            outf[idx] = v + resid[idx];               // f32 store to d_out
          }
        }
      }
    }
  }
}

// ---------------- Attention pass 1: per-chunk kv partial P_c = (k*kdec)^T @ v ----------------
// grid 1024 = bh*32 + c. Output P[bid] as f32 64x64 in (e, dd) layout.
__global__ __launch_bounds__(256) void attn_kv_kernel(
    const u16* __restrict__ k, const u16* __restrict__ v, float* __restrict__ P) {
  constexpr int LT = 136;
  __shared__ __align__(16) u16 kT_s[64 * LT];
  __shared__ __align__(16) u16 vT_s[64 * LT];
  __shared__ float kdec[128];
  int bid = blockIdx.x;
  int bh = bid >> 5;
  float sl = exp2f(-(float)((bh & 7) + 1));
  int t = threadIdx.x, lane = t & 63, wid = t >> 6;
  for (int i = t; i < 128; i += 256) kdec[i] = expf(-sl * (float)(128 - i));
  const u16* kb = k + (size_t)bid * 8192;
  const u16* vb = v + (size_t)bid * 8192;
  __syncthreads();
  int fr = lane & 15, fk = (lane >> 4) * 8, fq = lane >> 4;
#pragma unroll
  for (int i = 0; i < 16; ++i) {
    int seg = t + i * 256;
    int j = seg >> 5, dd = (seg & 31) * 2;
    unsigned int kp = *(const unsigned int*)&kb[(size_t)j * 64 + dd];
    float kd = kdec[j];
    kT_s[dd * LT + j] = f2b(b2f((u16)(kp & 0xFFFFu)) * kd);
    kT_s[(dd + 1) * LT + j] = f2b(b2f((u16)(kp >> 16)) * kd);
    unsigned int vp = *(const unsigned int*)&vb[(size_t)j * 64 + dd];
    vT_s[dd * LT + j] = (u16)(vp & 0xFFFFu);
    vT_s[(dd + 1) * LT + j] = (u16)(vp >> 16);
  }
  __syncthreads();
  f32x4 accKV[4] = {};
#pragma unroll
  for (int kk = 0; kk < 4; ++kk) {
    bf16x8 akt = *(const bf16x8*)&kT_s[(wid * 16 + fr) * LT + kk * 32 + fk];
#pragma unroll
    for (int j = 0; j < 4; ++j) {
      bf16x8 bvt = *(const bf16x8*)&vT_s[(j * 16 + fr) * LT + kk * 32 + fk];
      accKV[j] = __builtin_amdgcn_mfma_f32_16x16x32_bf16(akt, bvt, accKV[j], 0, 0, 0);
    }
  }
  // park P^T (e, dd) into f32 LDS (overlay kT_s), stride 68 to spread banks
  float* PT = (float*)kT_s;      // 64*68*4 = 17408 B <= kT_s 34816 B
  __syncthreads();
#pragma unroll
  for (int j = 0; j < 4; ++j)
#pragma unroll
    for (int jj = 0; jj < 4; ++jj) {
      int dd = wid * 16 + fq * 4 + jj;
      int e = j * 16 + fr;
      PT[e * 68 + dd] = accKV[j][jj];
    }
  __syncthreads();
  float* Pg = P + (size_t)bid * 4096;
  int e = t >> 2, d0 = (t & 3) * 16;
#pragma unroll
  for (int g = 0; g < 4; ++g) {
    f32x4 val = *(const f32x4*)&PT[e * 68 + d0 + g * 4];
    *(f32x4*)&Pg[(size_t)e * 64 + d0 + g * 4] = val;
  }
}

// ---------------- Attention pass 2: scan kv state; emit pre-chunk state as bf16 (e,d) ----------------
__global__ __launch_bounds__(256) void attn_scan_kernel(
    const float* __restrict__ P, u16* __restrict__ kvst) {
  int bh = blockIdx.x, t = threadIdx.x;
  float sl = exp2f(-(float)((bh & 7) + 1));
  float cdec = expf(-sl * 128.0f);
  float kv[16];
#pragma unroll
  for (int i = 0; i < 16; ++i) kv[i] = 0.f;
  for (int c = 0; c < 32; ++c) {
    size_t off = (((size_t)bh * 32 + c) * 4096) + (size_t)t * 16;
    union { u16 st[16]; uint4 v4[4]; } u;
#pragma unroll
    for (int i = 0; i < 16; ++i) u.st[i] = f2b(kv[i]);
    *(uint4*)&kvst[off] = u.v4[0];
    *(uint4*)&kvst[off + 8] = u.v4[1];
#pragma unroll
    for (int g = 0; g < 4; ++g) {
      f32x4 p = *(const f32x4*)&P[off + g * 4];
#pragma unroll
      for (int e = 0; e < 4; ++e) kv[g * 4 + e] = cdec * kv[g * 4 + e] + p[e];
    }
  }
}

// ---------------- Attention pass 3: out_c = masked(QK^T)@V + qdec*(Q@kv_state) ----------------
__global__ __launch_bounds__(256) void attn_out_kernel(
    const u16* __restrict__ q, const u16* __restrict__ k, const u16* __restrict__ v,
    const u16* __restrict__ kvst, u16* __restrict__ o) {
  constexpr int LQ = 72, LT = 136, LS = 136, LKV = 72;
  __shared__ __align__(16) u16 sm[31744];
  u16* q_s  = sm;              // 128*72
  u16* k_s  = sm + 9216;       // 128*72
  u16* vT_s = sm + 18432;      // 64*136
  u16* kvT_s = sm + 27136;     // 64*72
  u16* S_s  = sm;              // 128*136 overlays q_s+k_s (dead after S/inter MFMA)
  __shared__ float rowf[128], colf[128];
  int bid = blockIdx.x;
  int bh = bid >> 5;
  float sl = exp2f(-(float)((bh & 7) + 1));
  int t = threadIdx.x, lane = t & 63, wid = t >> 6;
  for (int i = t; i < 128; i += 256) {
    rowf[i] = expf(-sl * i);
    colf[i] = expf(sl * i);
  }
  const u16* qb = q + (size_t)bid * 8192;
  const u16* kb = k + (size_t)bid * 8192;
  const u16* vb = v + (size_t)bid * 8192;
  const u16* kvb = kvst + (size_t)bid * 4096;
  u16* ob = o + (size_t)bid * 8192;
  int fr = lane & 15, fk = (lane >> 4) * 8, fq = lane >> 4;
#pragma unroll
  for (int i = 0; i < 4; ++i) {        // q,k row-major
    int seg = t + i * 256;
    int r = seg >> 3, cc = (seg & 7) * 8;
    *(uint4*)&q_s[r * LQ + cc] = *(const uint4*)&qb[(size_t)r * 64 + cc];
    *(uint4*)&k_s[r * LQ + cc] = *(const uint4*)&kb[(size_t)r * 64 + cc];
  }
#pragma unroll
  for (int i = 0; i < 16; ++i) {       // vT transpose
    int seg = t + i * 256;
    int j = seg >> 5, dd = (seg & 31) * 2;
    unsigned int vp = *(const unsigned int*)&vb[(size_t)j * 64 + dd];
    vT_s[dd * LT + j] = (u16)(vp & 0xFFFFu);
    vT_s[(dd + 1) * LT + j] = (u16)(vp >> 16);
  }
#pragma unroll
  for (int i = 0; i < 2; ++i) {        // kv state straight copy (already (e,d))
    int seg = t + i * 256;
    int e = seg >> 3, dd = (seg & 7) * 8;
    *(uint4*)&kvT_s[e * LKV + dd] = *(const uint4*)&kvb[(size_t)e * 64 + dd];
  }
  __syncthreads();
  // S = Q K^T and inter = Q @ kv  (wave owns q-rows [wid*32, +32))
  f32x4 accS[2][8] = {};
  f32x4 accI[2][4] = {};
#pragma unroll
  for (int kk = 0; kk < 2; ++kk) {
    bf16x8 aq0 = *(const bf16x8*)&q_s[(wid * 32 + fr) * LQ + kk * 32 + fk];
    bf16x8 aq1 = *(const bf16x8*)&q_s[(wid * 32 + 16 + fr) * LQ + kk * 32 + fk];
#pragma unroll
    for (int j = 0; j < 8; ++j) {
      bf16x8 bk = *(const bf16x8*)&k_s[(j * 16 + fr) * LQ + kk * 32 + fk];
      accS[0][j] = __builtin_amdgcn_mfma_f32_16x16x32_bf16(aq0, bk, accS[0][j], 0, 0, 0);
      accS[1][j] = __builtin_amdgcn_mfma_f32_16x16x32_bf16(aq1, bk, accS[1][j], 0, 0, 0);
    }
#pragma unroll
    for (int j = 0; j < 4; ++j) {
      bf16x8 bkv = *(const bf16x8*)&kvT_s[(j * 16 + fr) * LKV + kk * 32 + fk];
      accI[0][j] = __builtin_amdgcn_mfma_f32_16x16x32_bf16(aq0, bkv, accI[0][j], 0, 0, 0);
      accI[1][j] = __builtin_amdgcn_mfma_f32_16x16x32_bf16(aq1, bkv, accI[1][j], 0, 0, 0);
    }
  }
  __syncthreads();   // q_s,k_s now dead -> S_s region reusable
#pragma unroll
  for (int i = 0; i < 2; ++i)
#pragma unroll
    for (int j = 0; j < 8; ++j)
#pragma unroll
      for (int jj = 0; jj < 4; ++jj) {
        int si = wid * 32 + i * 16 + fq * 4 + jj;
        int sj = j * 16 + fr;
        float val = (si >= sj) ? accS[i][j][jj] * rowf[si] * colf[sj] : 0.0f;
        S_s[si * LS + sj] = f2b(val);
      }
  __syncthreads();
  // intra = S' @ V
  f32x4 accO[2][4] = {};
#pragma unroll
  for (int kk = 0; kk < 4; ++kk) {
    bf16x8 as0 = *(const bf16x8*)&S_s[(wid * 32 + fr) * LS + kk * 32 + fk];
    bf16x8 as1 = *(const bf16x8*)&S_s[(wid * 32 + 16 + fr) * LS + kk * 32 + fk];
#pragma unroll
    for (int j = 0; j < 4; ++j) {
      bf16x8 bvt = *(const bf16x8*)&vT_s[(j * 16 + fr) * LT + kk * 32 + fk];
      accO[0][j] = __builtin_amdgcn_mfma_f32_16x16x32_bf16(as0, bvt, accO[0][j], 0, 0, 0);
      accO[1][j] = __builtin_amdgcn_mfma_f32_16x16x32_bf16(as1, bvt, accO[1][j], 0, 0, 0);
    }
  }
#pragma unroll
  for (int i = 0; i < 2; ++i)
#pragma unroll
    for (int j = 0; j < 4; ++j)
#pragma unroll
      for (int jj = 0; jj < 4; ++jj) {
        int li = wid * 32 + i * 16 + fq * 4 + jj;
        int e = j * 16 + fr;
        float val = accO[i][j][jj] + rowf[li] * accI[i][j][jj];
        ob[(size_t)li * 64 + e] = f2b(val);
      }
}

extern "C" void kernel_launch(void* const* d_in, const int* in_sizes, int n_in,
                              void* d_out, int out_size, void* d_ws, size_t ws_size,
                              hipStream_t stream) {
  const float* x      = (const float*)d_in[0];
  const float* ln1_w  = (const float*)d_in[1];
  const float* ln1_b  = (const float*)d_in[2];
  const float* rel    = (const float*)d_in[3];
  const float* qkv_w  = (const float*)d_in[4];
  const float* qkv_b  = (const float*)d_in[5];
  const float* gq     = (const float*)d_in[6];
  const float* gk     = (const float*)d_in[7];
  const float* proj_w = (const float*)d_in[8];
  const float* proj_b = (const float*)d_in[9];
  const float* ln2_w  = (const float*)d_in[10];
  const float* ln2_b  = (const float*)d_in[11];
  const float* fc1_w  = (const float*)d_in[12];
  const float* fc1_b  = (const float*)d_in[13];
  const float* fc2_w  = (const float*)d_in[14];
  const float* fc2_b  = (const float*)d_in[15];

  char* ws = (char*)d_ws;
  size_t off = 0;
  auto alloc = [&](size_t bytes) { char* p = ws + off; off += (bytes + 255) & ~(size_t)255; return p; };
  u16* w_qkv  = (u16*)alloc((size_t)1536 * 512 * 2);
  u16* w_proj = (u16*)alloc((size_t)512 * 512 * 2);
  u16* w_fc1  = (u16*)alloc((size_t)2048 * 512 * 2);
  u16* w_fc2  = (u16*)alloc((size_t)512 * 2048 * 2);
  u16* h_buf  = (u16*)alloc((size_t)16384 * 512 * 2);   // ln1 out; reused for ln2 out
  u16* q_buf  = (u16*)alloc((size_t)8388608 * 2);
  u16* k_buf  = (u16*)alloc((size_t)8388608 * 2);
  u16* v_buf  = (u16*)alloc((size_t)8388608 * 2);
  u16* o_buf  = (u16*)alloc((size_t)8388608 * 2);
  float* x2   = (float*)alloc((size_t)8388608 * 4);
  u16* mid    = q_buf;   // 16384x2048 bf16 overlays q..o (dead after attention/proj)
  // attention scratch overlays x2 (x2 written only after attention):
  float* P_glob  = x2;                       // 1024*4096 f32 = 16.8 MB
  u16*   kv_state = (u16*)(x2 + 4194304);    // 1024*4096 bf16 = 8.4 MB

  conv_f2b_kernel<<<512, 256, 0, stream>>>(qkv_w, w_qkv, 1536 * 512);
  conv_f2b_kernel<<<512, 256, 0, stream>>>(proj_w, w_proj, 512 * 512);
  conv_f2b_kernel<<<512, 256, 0, stream>>>(fc1_w, w_fc1, 2048 * 512);
  conv_f2b_kernel<<<512, 256, 0, stream>>>(fc2_w, w_fc2, 512 * 2048);

  ln_kernel<1><<<16384, 256, 0, stream>>>(x, ln1_w, ln1_b, rel, h_buf);

  gemm_bt_kernel<0><<<dim3(12, 128), 256, 0, stream>>>(h_buf, w_qkv, qkv_b, 16384, 1536, 512,
      nullptr, nullptr, q_buf, k_buf, v_buf, nullptr, gq, gk);

  attn_kv_kernel<<<1024, 256, 0, stream>>>(k_buf, v_buf, P_glob);
  attn_scan_kernel<<<32, 256, 0, stream>>>(P_glob, kv_state);
  attn_out_kernel<<<1024, 256, 0, stream>>>(q_buf, k_buf, v_buf, kv_state, o_buf);

  gemm_bt_kernel<1><<<dim3(4, 128), 256, 0, stream>>>(o_buf, w_proj, proj_b, 16384, 512, 512,
      x, nullptr, nullptr, nullptr, nullptr, x2, nullptr, nullptr);

  ln_kernel<0><<<16384, 256, 0, stream>>>(x2, ln2_w, ln2_b, nullptr, h_buf);

  gemm_bt_kernel<2><<<dim3(16, 128), 256, 0, stream>>>(h_buf, w_fc1, fc1_b, 16384, 2048, 512,
      nullptr, mid, nullptr, nullptr, nullptr, nullptr, nullptr, nullptr);

  gemm_bt_kernel<3><<<dim3(4, 128), 256, 0, stream>>>(mid, w_fc2, fc2_b, 16384, 512, 2048,
      x2, nullptr, nullptr, nullptr, nullptr, (float*)d_out, nullptr, nullptr);

  (void)in_sizes; (void)n_in; (void)out_size; (void)ws_size;
}

// Round 8
// 290.377 us; speedup vs baseline: 7.2164x; 1.1470x over previous
//
#include <hip/hip_runtime.h>
#include <math.h>

typedef unsigned short u16;
typedef __bf16 bf16x8 __attribute__((ext_vector_type(8)));
typedef float f32x4 __attribute__((ext_vector_type(4)));

#define DEVI static __device__ __forceinline__

DEVI float b2f(u16 u) { union { unsigned int i; float f; } w; w.i = ((unsigned int)u) << 16; return w.f; }
DEVI u16 f2b(float f) {
  union { float f; unsigned int i; } w; w.f = f;
  unsigned int r = (w.i + 0x7FFFu + ((w.i >> 16) & 1u)) >> 16;
  return (u16)r;
}

// Exact-GELU via A&S 7.1.26 erf (|err|<=1.5e-7): ~18 VALU ops, hw exp/rcp.
DEVI float fast_gelu(float v) {
  float z = fabsf(v) * 0.70710678118654752f;
  float t = __builtin_amdgcn_rcpf(1.0f + 0.3275911f * z);
  float p = ((((1.061405429f * t - 1.453152027f) * t + 1.421413741f) * t
              - 0.284496736f) * t + 0.254829592f) * t;
  float er = 1.0f - p * __expf(-z * z);
  er = (v < 0.0f) ? -er : er;
  return 0.5f * v * (1.0f + er);
}

// ---------------- f32 -> bf16 weight conversion ----------------
__global__ void conv_f2b_kernel(const float* __restrict__ s, u16* __restrict__ d, int n) {
  int i = blockIdx.x * 256 + threadIdx.x;
  int st = gridDim.x * 256;
  for (; i < n; i += st) d[i] = f2b(s[i]);
}

// ---------------- LayerNorm (+optional rel_bias), f32 in -> bf16 out ----------------
template<int ADD_REL>
__global__ __launch_bounds__(256) void ln_kernel(
    const float* __restrict__ x, const float* __restrict__ w, const float* __restrict__ bb,
    const float* __restrict__ rel, u16* __restrict__ out) {
  int row = blockIdx.x;            // 0..16383 = b*4096 + l
  int t = threadIdx.x;             // 256
  const float* xr = x + (size_t)row * 512;
  float v0 = xr[t], v1 = xr[t + 256];
  float s = v0 + v1, ss = v0 * v0 + v1 * v1;
#pragma unroll
  for (int o = 32; o > 0; o >>= 1) { s += __shfl_down(s, o); ss += __shfl_down(ss, o); }
  __shared__ float rs[4], rss[4];
  int lane = t & 63, wid = t >> 6;
  if (lane == 0) { rs[wid] = s; rss[wid] = ss; }
  __syncthreads();
  s = rs[0] + rs[1] + rs[2] + rs[3];
  ss = rss[0] + rss[1] + rss[2] + rss[3];
  float mu = s * (1.0f / 512.0f);
  float inv = rsqrtf(ss * (1.0f / 512.0f) - mu * mu + 1e-5f);
  float o0 = (v0 - mu) * inv * w[t] + bb[t];
  float o1 = (v1 - mu) * inv * w[t + 256] + bb[t + 256];
  if (ADD_REL) {
    const float* rr = rel + (size_t)(row & 4095) * 512;
    o0 += rr[t]; o1 += rr[t + 256];
  }
  u16* orow = out + (size_t)row * 512;
  orow[t] = f2b(o0);
  orow[t + 256] = f2b(o1);
}

// ---------------- GEMM: C[M,N] = A[M,K] @ W[N,K]^T + bias, bf16 MFMA ----------------
// m97 structure: global_load_lds(16B) staging into LINEAR [128][32] LDS, 2 barriers/K-step.
// 1-D grid + XCD-bijective swizzle (nwg % 8 == 0 for all our launches).
// EPI: 0=qkv scatter + fused RMS on q/k, 1=proj+residual->f32, 2=gelu->bf16, 3=fc2+residual->f32
template<int EPI>
__global__ __launch_bounds__(256) void gemm_bt_kernel(
    const u16* __restrict__ A, const u16* __restrict__ W,
    const float* __restrict__ bias, int M, int N, int K, int NBN,
    const float* __restrict__ resid, u16* __restrict__ outb,
    u16* __restrict__ q_out, u16* __restrict__ k_out, u16* __restrict__ v_out,
    float* __restrict__ outf, const float* __restrict__ gq, const float* __restrict__ gk) {
  __shared__ u16 As[128 * 32];                 // linear, no pad (global_load_lds dest)
  __shared__ u16 Bs[128 * 32];
  int nwg = gridDim.x, wg = blockIdx.x;
  int wgs = (wg & 7) * (nwg >> 3) + (wg >> 3);     // XCD chunking (bijective: nwg%8==0)
  int bn = wgs % NBN, bm = wgs / NBN;
  int m0 = bm * 128, n0 = bn * 128;
  int t = threadIdx.x, lane = t & 63, wid = t >> 6;
  int wr = (wid >> 1) * 64, wc = (wid & 1) * 64;    // wave -> 64x64 quadrant
  int fr = lane & 15, fk = (lane >> 4) * 8;
  // staging: wave wid stages rows [wid*32, wid*32+32); chunk = 16 rows = 1KB.
  int srow = wid * 32 + (lane >> 2);
  int scol = (lane & 3) * 8;
  const u16* gA = A + (size_t)(m0 + srow) * K + scol;
  const u16* gB = W + (size_t)(n0 + srow) * K + scol;
  u16* lA = &As[wid * 1024];                   // wave-uniform LDS base
  u16* lB = &Bs[wid * 1024];
  f32x4 acc[4][4] = {};
  for (int k0 = 0; k0 < K; k0 += 32) {
    __builtin_amdgcn_global_load_lds(gA + k0,          lA,       16, 0, 0);
    __builtin_amdgcn_global_load_lds(gA + k0 + 16 * K, lA + 512, 16, 0, 0);
    __builtin_amdgcn_global_load_lds(gB + k0,          lB,       16, 0, 0);
    __builtin_amdgcn_global_load_lds(gB + k0 + 16 * K, lB + 512, 16, 0, 0);
    __syncthreads();
    bf16x8 af[4], bfr[4];
#pragma unroll
    for (int i = 0; i < 4; ++i) af[i] = *(const bf16x8*)&As[(wr + i * 16 + fr) * 32 + fk];
#pragma unroll
    for (int j = 0; j < 4; ++j) bfr[j] = *(const bf16x8*)&Bs[(wc + j * 16 + fr) * 32 + fk];
#pragma unroll
    for (int i = 0; i < 4; ++i)
#pragma unroll
      for (int j = 0; j < 4; ++j)
        acc[i][j] = __builtin_amdgcn_mfma_f32_16x16x32_bf16(af[i], bfr[j], acc[i][j], 0, 0, 0);
    __syncthreads();
  }
  int fq = lane >> 4;
  if (EPI == 0) {
    // quadrant base is 64-aligned -> covers exactly one (which, head) d-range
    int nb = n0 + wc;
    int which = nb >> 9, head = (nb >> 6) & 7;
    const float* gg = (which == 0) ? gq : gk;
#pragma unroll
    for (int i = 0; i < 4; ++i) {
#pragma unroll
      for (int jj = 0; jj < 4; ++jj) {
        int gm = m0 + wr + i * 16 + fq * 4 + jj;
        int b = gm >> 12, l = gm & 4095;
        float v[4]; float ssum = 0.f;
#pragma unroll
        for (int j = 0; j < 4; ++j) {
          v[j] = acc[i][j][jj] + bias[nb + j * 16 + fr];
          ssum += v[j] * v[j];
        }
        u16* dst = (which == 0) ? q_out : (which == 1) ? k_out : v_out;
        size_t rowbase = (((size_t)(b * 8 + head) * 4096) + l) * 64;
        if (which == 2) {
#pragma unroll
          for (int j = 0; j < 4; ++j) dst[rowbase + j * 16 + fr] = f2b(v[j]);
        } else {
          // fused RMSNorm over the row's 64 d-values (4 regs x 16 fr-lanes)
#pragma unroll
          for (int o = 1; o < 16; o <<= 1) ssum += __shfl_xor(ssum, o);
          float inv = 8.0f / fmaxf(sqrtf(ssum), 1e-12f);
#pragma unroll
          for (int j = 0; j < 4; ++j)
            dst[rowbase + j * 16 + fr] = f2b(v[j] * inv * gg[head * 64 + j * 16 + fr]);
        }
      }
    }
  } else {
#pragma unroll
    for (int i = 0; i < 4; ++i) {
#pragma unroll
      for (int j = 0; j < 4; ++j) {
#pragma unroll
        for (int jj = 0; jj < 4; ++jj) {
          int gm = m0 + wr + i * 16 + fq * 4 + jj;
          int gn = n0 + wc + j * 16 + fr;
          float v = acc[i][j][jj] + bias[gn];
          if (EPI == 1) {
            size_t idx = (size_t)gm * 512 + gn;
            outf[idx] = v + resid[idx];
          } else if (EPI == 2) {
            outb[(size_t)gm * (size_t)N + gn] = f2b(fast_gelu(v));
          } else {
            size_t idx = (size_t)gm * 512 + gn;
            outf[idx] = v + resid[idx];               // f32 store to d_out
          }
        }
      }
    }
  }
}

// ---------------- Attention pass 1: per-chunk kv partial P_c = (k*kdec)^T @ v ----------------
// grid 1024 = bh*32 + c. Output P[bid] as f32 64x64 in (e, dd) layout.
__global__ __launch_bounds__(256) void attn_kv_kernel(
    const u16* __restrict__ k, const u16* __restrict__ v, float* __restrict__ P) {
  constexpr int LT = 136;
  __shared__ __align__(16) u16 kT_s[64 * LT];
  __shared__ __align__(16) u16 vT_s[64 * LT];
  __shared__ float kdec[128];
  int bid = blockIdx.x;
  int bh = bid >> 5;
  float sl = exp2f(-(float)((bh & 7) + 1));
  int t = threadIdx.x, lane = t & 63, wid = t >> 6;
  for (int i = t; i < 128; i += 256) kdec[i] = expf(-sl * (float)(128 - i));
  const u16* kb = k + (size_t)bid * 8192;
  const u16* vb = v + (size_t)bid * 8192;
  __syncthreads();
  int fr = lane & 15, fk = (lane >> 4) * 8, fq = lane >> 4;
#pragma unroll
  for (int i = 0; i < 16; ++i) {
    int seg = t + i * 256;
    int j = seg >> 5, dd = (seg & 31) * 2;
    unsigned int kp = *(const unsigned int*)&kb[(size_t)j * 64 + dd];
    float kd = kdec[j];
    kT_s[dd * LT + j] = f2b(b2f((u16)(kp & 0xFFFFu)) * kd);
    kT_s[(dd + 1) * LT + j] = f2b(b2f((u16)(kp >> 16)) * kd);
    unsigned int vp = *(const unsigned int*)&vb[(size_t)j * 64 + dd];
    vT_s[dd * LT + j] = (u16)(vp & 0xFFFFu);
    vT_s[(dd + 1) * LT + j] = (u16)(vp >> 16);
  }
  __syncthreads();
  f32x4 accKV[4] = {};
#pragma unroll
  for (int kk = 0; kk < 4; ++kk) {
    bf16x8 akt = *(const bf16x8*)&kT_s[(wid * 16 + fr) * LT + kk * 32 + fk];
#pragma unroll
    for (int j = 0; j < 4; ++j) {
      bf16x8 bvt = *(const bf16x8*)&vT_s[(j * 16 + fr) * LT + kk * 32 + fk];
      accKV[j] = __builtin_amdgcn_mfma_f32_16x16x32_bf16(akt, bvt, accKV[j], 0, 0, 0);
    }
  }
  // park P^T (e, dd) into f32 LDS (overlay kT_s), stride 68 to spread banks
  float* PT = (float*)kT_s;      // 64*68*4 = 17408 B <= kT_s 34816 B
  __syncthreads();
#pragma unroll
  for (int j = 0; j < 4; ++j)
#pragma unroll
    for (int jj = 0; jj < 4; ++jj) {
      int dd = wid * 16 + fq * 4 + jj;
      int e = j * 16 + fr;
      PT[e * 68 + dd] = accKV[j][jj];
    }
  __syncthreads();
  float* Pg = P + (size_t)bid * 4096;
  int e = t >> 2, d0 = (t & 3) * 16;
#pragma unroll
  for (int g = 0; g < 4; ++g) {
    f32x4 val = *(const f32x4*)&PT[e * 68 + d0 + g * 4];
    *(f32x4*)&Pg[(size_t)e * 64 + d0 + g * 4] = val;
  }
}

// ---------------- Attention pass 2: scan kv state; emit pre-chunk state as bf16 (e,d) ----------------
__global__ __launch_bounds__(256) void attn_scan_kernel(
    const float* __restrict__ P, u16* __restrict__ kvst) {
  int bh = blockIdx.x, t = threadIdx.x;
  float sl = exp2f(-(float)((bh & 7) + 1));
  float cdec = expf(-sl * 128.0f);
  float kv[16];
#pragma unroll
  for (int i = 0; i < 16; ++i) kv[i] = 0.f;
  for (int c = 0; c < 32; ++c) {
    size_t off = (((size_t)bh * 32 + c) * 4096) + (size_t)t * 16;
    union { u16 st[16]; uint4 v4[4]; } u;
#pragma unroll
    for (int i = 0; i < 16; ++i) u.st[i] = f2b(kv[i]);
    *(uint4*)&kvst[off] = u.v4[0];
    *(uint4*)&kvst[off + 8] = u.v4[1];
#pragma unroll
    for (int g = 0; g < 4; ++g) {
      f32x4 p = *(const f32x4*)&P[off + g * 4];
#pragma unroll
      for (int e = 0; e < 4; ++e) kv[g * 4 + e] = cdec * kv[g * 4 + e] + p[e];
    }
  }
}

// ---------------- Attention pass 3: out_c = masked(QK^T)@V + qdec*(Q@kv_state) ----------------
__global__ __launch_bounds__(256) void attn_out_kernel(
    const u16* __restrict__ q, const u16* __restrict__ k, const u16* __restrict__ v,
    const u16* __restrict__ kvst, u16* __restrict__ o) {
  constexpr int LQ = 72, LT = 136, LS = 136, LKV = 72;
  __shared__ __align__(16) u16 sm[31744];
  u16* q_s  = sm;              // 128*72
  u16* k_s  = sm + 9216;       // 128*72
  u16* vT_s = sm + 18432;      // 64*136
  u16* kvT_s = sm + 27136;     // 64*72
  u16* S_s  = sm;              // 128*136 overlays q_s+k_s (dead after S/inter MFMA)
  __shared__ float rowf[128], colf[128];
  int bid = blockIdx.x;
  int bh = bid >> 5;
  float sl = exp2f(-(float)((bh & 7) + 1));
  int t = threadIdx.x, lane = t & 63, wid = t >> 6;
  for (int i = t; i < 128; i += 256) {
    rowf[i] = expf(-sl * i);
    colf[i] = expf(sl * i);
  }
  const u16* qb = q + (size_t)bid * 8192;
  const u16* kb = k + (size_t)bid * 8192;
  const u16* vb = v + (size_t)bid * 8192;
  const u16* kvb = kvst + (size_t)bid * 4096;
  u16* ob = o + (size_t)bid * 8192;
  int fr = lane & 15, fk = (lane >> 4) * 8, fq = lane >> 4;
#pragma unroll
  for (int i = 0; i < 4; ++i) {        // q,k row-major
    int seg = t + i * 256;
    int r = seg >> 3, cc = (seg & 7) * 8;
    *(uint4*)&q_s[r * LQ + cc] = *(const uint4*)&qb[(size_t)r * 64 + cc];
    *(uint4*)&k_s[r * LQ + cc] = *(const uint4*)&kb[(size_t)r * 64 + cc];
  }
#pragma unroll
  for (int i = 0; i < 16; ++i) {       // vT transpose
    int seg = t + i * 256;
    int j = seg >> 5, dd = (seg & 31) * 2;
    unsigned int vp = *(const unsigned int*)&vb[(size_t)j * 64 + dd];
    vT_s[dd * LT + j] = (u16)(vp & 0xFFFFu);
    vT_s[(dd + 1) * LT + j] = (u16)(vp >> 16);
  }
#pragma unroll
  for (int i = 0; i < 2; ++i) {        // kv state straight copy (already (e,d))
    int seg = t + i * 256;
    int e = seg >> 3, dd = (seg & 7) * 8;
    *(uint4*)&kvT_s[e * LKV + dd] = *(const uint4*)&kvb[(size_t)e * 64 + dd];
  }
  __syncthreads();
  // S = Q K^T and inter = Q @ kv  (wave owns q-rows [wid*32, +32))
  f32x4 accS[2][8] = {};
  f32x4 accI[2][4] = {};
#pragma unroll
  for (int kk = 0; kk < 2; ++kk) {
    bf16x8 aq0 = *(const bf16x8*)&q_s[(wid * 32 + fr) * LQ + kk * 32 + fk];
    bf16x8 aq1 = *(const bf16x8*)&q_s[(wid * 32 + 16 + fr) * LQ + kk * 32 + fk];
#pragma unroll
    for (int j = 0; j < 8; ++j) {
      bf16x8 bk = *(const bf16x8*)&k_s[(j * 16 + fr) * LQ + kk * 32 + fk];
      accS[0][j] = __builtin_amdgcn_mfma_f32_16x16x32_bf16(aq0, bk, accS[0][j], 0, 0, 0);
      accS[1][j] = __builtin_amdgcn_mfma_f32_16x16x32_bf16(aq1, bk, accS[1][j], 0, 0, 0);
    }
#pragma unroll
    for (int j = 0; j < 4; ++j) {
      bf16x8 bkv = *(const bf16x8*)&kvT_s[(j * 16 + fr) * LKV + kk * 32 + fk];
      accI[0][j] = __builtin_amdgcn_mfma_f32_16x16x32_bf16(aq0, bkv, accI[0][j], 0, 0, 0);
      accI[1][j] = __builtin_amdgcn_mfma_f32_16x16x32_bf16(aq1, bkv, accI[1][j], 0, 0, 0);
    }
  }
  __syncthreads();   // q_s,k_s now dead -> S_s region reusable
#pragma unroll
  for (int i = 0; i < 2; ++i)
#pragma unroll
    for (int j = 0; j < 8; ++j)
#pragma unroll
      for (int jj = 0; jj < 4; ++jj) {
        int si = wid * 32 + i * 16 + fq * 4 + jj;
        int sj = j * 16 + fr;
        float val = (si >= sj) ? accS[i][j][jj] * rowf[si] * colf[sj] : 0.0f;
        S_s[si * LS + sj] = f2b(val);
      }
  __syncthreads();
  // intra = S' @ V
  f32x4 accO[2][4] = {};
#pragma unroll
  for (int kk = 0; kk < 4; ++kk) {
    bf16x8 as0 = *(const bf16x8*)&S_s[(wid * 32 + fr) * LS + kk * 32 + fk];
    bf16x8 as1 = *(const bf16x8*)&S_s[(wid * 32 + 16 + fr) * LS + kk * 32 + fk];
#pragma unroll
    for (int j = 0; j < 4; ++j) {
      bf16x8 bvt = *(const bf16x8*)&vT_s[(j * 16 + fr) * LT + kk * 32 + fk];
      accO[0][j] = __builtin_amdgcn_mfma_f32_16x16x32_bf16(as0, bvt, accO[0][j], 0, 0, 0);
      accO[1][j] = __builtin_amdgcn_mfma_f32_16x16x32_bf16(as1, bvt, accO[1][j], 0, 0, 0);
    }
  }
#pragma unroll
  for (int i = 0; i < 2; ++i)
#pragma unroll
    for (int j = 0; j < 4; ++j)
#pragma unroll
      for (int jj = 0; jj < 4; ++jj) {
        int li = wid * 32 + i * 16 + fq * 4 + jj;
        int e = j * 16 + fr;
        float val = accO[i][j][jj] + rowf[li] * accI[i][j][jj];
        ob[(size_t)li * 64 + e] = f2b(val);
      }
}

extern "C" void kernel_launch(void* const* d_in, const int* in_sizes, int n_in,
                              void* d_out, int out_size, void* d_ws, size_t ws_size,
                              hipStream_t stream) {
  const float* x      = (const float*)d_in[0];
  const float* ln1_w  = (const float*)d_in[1];
  const float* ln1_b  = (const float*)d_in[2];
  const float* rel    = (const float*)d_in[3];
  const float* qkv_w  = (const float*)d_in[4];
  const float* qkv_b  = (const float*)d_in[5];
  const float* gq     = (const float*)d_in[6];
  const float* gk     = (const float*)d_in[7];
  const float* proj_w = (const float*)d_in[8];
  const float* proj_b = (const float*)d_in[9];
  const float* ln2_w  = (const float*)d_in[10];
  const float* ln2_b  = (const float*)d_in[11];
  const float* fc1_w  = (const float*)d_in[12];
  const float* fc1_b  = (const float*)d_in[13];
  const float* fc2_w  = (const float*)d_in[14];
  const float* fc2_b  = (const float*)d_in[15];

  char* ws = (char*)d_ws;
  size_t off = 0;
  auto alloc = [&](size_t bytes) { char* p = ws + off; off += (bytes + 255) & ~(size_t)255; return p; };
  u16* w_qkv  = (u16*)alloc((size_t)1536 * 512 * 2);
  u16* w_proj = (u16*)alloc((size_t)512 * 512 * 2);
  u16* w_fc1  = (u16*)alloc((size_t)2048 * 512 * 2);
  u16* w_fc2  = (u16*)alloc((size_t)512 * 2048 * 2);
  u16* h_buf  = (u16*)alloc((size_t)16384 * 512 * 2);   // ln1 out; reused for ln2 out
  u16* q_buf  = (u16*)alloc((size_t)8388608 * 2);
  u16* k_buf  = (u16*)alloc((size_t)8388608 * 2);
  u16* v_buf  = (u16*)alloc((size_t)8388608 * 2);
  u16* o_buf  = (u16*)alloc((size_t)8388608 * 2);
  float* x2   = (float*)alloc((size_t)8388608 * 4);
  u16* mid    = q_buf;   // 16384x2048 bf16 overlays q..o (dead after attention/proj)
  // attention scratch overlays x2 (x2 written only after attention):
  float* P_glob  = x2;                       // 1024*4096 f32 = 16.8 MB
  u16*   kv_state = (u16*)(x2 + 4194304);    // 1024*4096 bf16 = 8.4 MB

  conv_f2b_kernel<<<512, 256, 0, stream>>>(qkv_w, w_qkv, 1536 * 512);
  conv_f2b_kernel<<<512, 256, 0, stream>>>(proj_w, w_proj, 512 * 512);
  conv_f2b_kernel<<<512, 256, 0, stream>>>(fc1_w, w_fc1, 2048 * 512);
  conv_f2b_kernel<<<512, 256, 0, stream>>>(fc2_w, w_fc2, 512 * 2048);

  ln_kernel<1><<<16384, 256, 0, stream>>>(x, ln1_w, ln1_b, rel, h_buf);

  gemm_bt_kernel<0><<<1536, 256, 0, stream>>>(h_buf, w_qkv, qkv_b, 16384, 1536, 512, 12,
      nullptr, nullptr, q_buf, k_buf, v_buf, nullptr, gq, gk);

  attn_kv_kernel<<<1024, 256, 0, stream>>>(k_buf, v_buf, P_glob);
  attn_scan_kernel<<<32, 256, 0, stream>>>(P_glob, kv_state);
  attn_out_kernel<<<1024, 256, 0, stream>>>(q_buf, k_buf, v_buf, kv_state, o_buf);

  gemm_bt_kernel<1><<<512, 256, 0, stream>>>(o_buf, w_proj, proj_b, 16384, 512, 512, 4,
      x, nullptr, nullptr, nullptr, nullptr, x2, nullptr, nullptr);

  ln_kernel<0><<<16384, 256, 0, stream>>>(x2, ln2_w, ln2_b, nullptr, h_buf);

  gemm_bt_kernel<2><<<2048, 256, 0, stream>>>(h_buf, w_fc1, fc1_b, 16384, 2048, 512, 16,
      nullptr, mid, nullptr, nullptr, nullptr, nullptr, nullptr, nullptr);

  gemm_bt_kernel<3><<<512, 256, 0, stream>>>(mid, w_fc2, fc2_b, 16384, 512, 2048, 4,
      x2, nullptr, nullptr, nullptr, nullptr, (float*)d_out, nullptr, nullptr);

  (void)in_sizes; (void)n_in; (void)out_size; (void)ws_size;
}

// Round 9
// 279.973 us; speedup vs baseline: 7.4846x; 1.0372x over previous
//
#include <hip/hip_runtime.h>
#include <math.h>

typedef unsigned short u16;
typedef __bf16 bf16x8 __attribute__((ext_vector_type(8)));
typedef float f32x4 __attribute__((ext_vector_type(4)));

#define DEVI static __device__ __forceinline__

DEVI float b2f(u16 u) { union { unsigned int i; float f; } w; w.i = ((unsigned int)u) << 16; return w.f; }
DEVI u16 f2b(float f) {
  union { float f; unsigned int i; } w; w.f = f;
  unsigned int r = (w.i + 0x7FFFu + ((w.i >> 16) & 1u)) >> 16;
  return (u16)r;
}

// tanh-GELU: x * rcp(1 + exp2(-x*(c1 + c2*x^2))), max |err| vs exact ~3e-4.
DEVI float fast_gelu(float v) {
  float x2 = v * v;
  float p = fmaf(0.10294357f, x2, 2.30215855f);
  float ex = exp2f(-v * p);
  return v * __builtin_amdgcn_rcpf(1.0f + ex);
}

// ---------------- f32 -> bf16 weight conversion ----------------
__global__ void conv_f2b_kernel(const float* __restrict__ s, u16* __restrict__ d, int n) {
  int i = blockIdx.x * 256 + threadIdx.x;
  int st = gridDim.x * 256;
  for (; i < n; i += st) d[i] = f2b(s[i]);
}

// ---------------- LayerNorm (+optional rel_bias), f32 in -> bf16 out ----------------
template<int ADD_REL>
__global__ __launch_bounds__(256) void ln_kernel(
    const float* __restrict__ x, const float* __restrict__ w, const float* __restrict__ bb,
    const float* __restrict__ rel, u16* __restrict__ out) {
  int row = blockIdx.x;            // 0..16383 = b*4096 + l
  int t = threadIdx.x;             // 256
  const float* xr = x + (size_t)row * 512;
  float v0 = xr[t], v1 = xr[t + 256];
  float s = v0 + v1, ss = v0 * v0 + v1 * v1;
#pragma unroll
  for (int o = 32; o > 0; o >>= 1) { s += __shfl_down(s, o); ss += __shfl_down(ss, o); }
  __shared__ float rs[4], rss[4];
  int lane = t & 63, wid = t >> 6;
  if (lane == 0) { rs[wid] = s; rss[wid] = ss; }
  __syncthreads();
  s = rs[0] + rs[1] + rs[2] + rs[3];
  ss = rss[0] + rss[1] + rss[2] + rss[3];
  float mu = s * (1.0f / 512.0f);
  float inv = rsqrtf(ss * (1.0f / 512.0f) - mu * mu + 1e-5f);
  float o0 = (v0 - mu) * inv * w[t] + bb[t];
  float o1 = (v1 - mu) * inv * w[t + 256] + bb[t + 256];
  if (ADD_REL) {
    const float* rr = rel + (size_t)(row & 4095) * 512;
    o0 += rr[t]; o1 += rr[t + 256];
  }
  u16* orow = out + (size_t)row * 512;
  orow[t] = f2b(o0);
  orow[t + 256] = f2b(o1);
}

// ---------------- GEMM: C[M,N] = A[M,K] @ W[N,K]^T + bias, bf16 MFMA ----------------
// 2-phase double-buffered (T3-minimum): STAGE(next) -> ds_read+MFMA(cur) -> vmcnt(0)+barrier.
// global_load_lds(16B) into LINEAR [2][128][32] LDS; XCD-bijective swizzle (nwg%8==0).
// EPI: 0=qkv scatter + fused RMS on q/k, 1=proj+residual->f32, 2=gelu->bf16, 3=fc2+residual->f32
template<int EPI>
__global__ __launch_bounds__(256) void gemm_bt_kernel(
    const u16* __restrict__ A, const u16* __restrict__ W,
    const float* __restrict__ bias, int M, int N, int K, int NBN,
    const float* __restrict__ resid, u16* __restrict__ outb,
    u16* __restrict__ q_out, u16* __restrict__ k_out, u16* __restrict__ v_out,
    float* __restrict__ outf, const float* __restrict__ gq, const float* __restrict__ gk) {
  __shared__ u16 As[2][128 * 32];              // linear, no pad (global_load_lds dest)
  __shared__ u16 Bs[2][128 * 32];
  int nwg = gridDim.x, wg = blockIdx.x;
  int wgs = (wg & 7) * (nwg >> 3) + (wg >> 3);     // XCD chunking (bijective: nwg%8==0)
  int bn = wgs % NBN, bm = wgs / NBN;
  int m0 = bm * 128, n0 = bn * 128;
  int t = threadIdx.x, lane = t & 63, wid = t >> 6;
  int wr = (wid >> 1) * 64, wc = (wid & 1) * 64;    // wave -> 64x64 quadrant
  int fr = lane & 15, fk = (lane >> 4) * 8;
  // staging: wave wid stages rows [wid*32, wid*32+32); chunk = 16 rows = 1KB.
  int srow = wid * 32 + (lane >> 2);
  int scol = (lane & 3) * 8;
  const u16* gA = A + (size_t)(m0 + srow) * K + scol;
  const u16* gB = W + (size_t)(n0 + srow) * K + scol;
  f32x4 acc[4][4] = {};
  auto STAGE = [&](int sel, int k0) {
    u16* lA = &As[sel][wid * 1024];            // wave-uniform LDS base
    u16* lB = &Bs[sel][wid * 1024];
    __builtin_amdgcn_global_load_lds(gA + k0,          lA,       16, 0, 0);
    __builtin_amdgcn_global_load_lds(gA + k0 + 16 * K, lA + 512, 16, 0, 0);
    __builtin_amdgcn_global_load_lds(gB + k0,          lB,       16, 0, 0);
    __builtin_amdgcn_global_load_lds(gB + k0 + 16 * K, lB + 512, 16, 0, 0);
  };
  STAGE(0, 0);
  asm volatile("s_waitcnt vmcnt(0)" ::: "memory");
  __builtin_amdgcn_s_barrier();
  int cur = 0;
  for (int k0 = 0; k0 < K; k0 += 32) {
    if (k0 + 32 < K) STAGE(cur ^ 1, k0 + 32);  // prefetch next tile (uniform branch)
    bf16x8 af[4], bfr[4];
#pragma unroll
    for (int i = 0; i < 4; ++i) af[i] = *(const bf16x8*)&As[cur][(wr + i * 16 + fr) * 32 + fk];
#pragma unroll
    for (int j = 0; j < 4; ++j) bfr[j] = *(const bf16x8*)&Bs[cur][(wc + j * 16 + fr) * 32 + fk];
#pragma unroll
    for (int i = 0; i < 4; ++i)
#pragma unroll
      for (int j = 0; j < 4; ++j)
        acc[i][j] = __builtin_amdgcn_mfma_f32_16x16x32_bf16(af[i], bfr[j], acc[i][j], 0, 0, 0);
    asm volatile("s_waitcnt vmcnt(0)" ::: "memory");   // prefetch landed
    __builtin_amdgcn_s_barrier();                      // all waves done reading cur
    cur ^= 1;
  }
  int fq = lane >> 4;
  if (EPI == 0) {
    // quadrant base is 64-aligned -> covers exactly one (which, head) d-range
    int nb = n0 + wc;
    int which = nb >> 9, head = (nb >> 6) & 7;
    const float* gg = (which == 0) ? gq : gk;
#pragma unroll
    for (int i = 0; i < 4; ++i) {
#pragma unroll
      for (int jj = 0; jj < 4; ++jj) {
        int gm = m0 + wr + i * 16 + fq * 4 + jj;
        int b = gm >> 12, l = gm & 4095;
        float v[4]; float ssum = 0.f;
#pragma unroll
        for (int j = 0; j < 4; ++j) {
          v[j] = acc[i][j][jj] + bias[nb + j * 16 + fr];
          ssum += v[j] * v[j];
        }
        u16* dst = (which == 0) ? q_out : (which == 1) ? k_out : v_out;
        size_t rowbase = (((size_t)(b * 8 + head) * 4096) + l) * 64;
        if (which == 2) {
#pragma unroll
          for (int j = 0; j < 4; ++j) dst[rowbase + j * 16 + fr] = f2b(v[j]);
        } else {
          // fused RMSNorm over the row's 64 d-values (4 regs x 16 fr-lanes)
#pragma unroll
          for (int o = 1; o < 16; o <<= 1) ssum += __shfl_xor(ssum, o);
          float inv = 8.0f / fmaxf(sqrtf(ssum), 1e-12f);
#pragma unroll
          for (int j = 0; j < 4; ++j)
            dst[rowbase + j * 16 + fr] = f2b(v[j] * inv * gg[head * 64 + j * 16 + fr]);
        }
      }
    }
  } else {
#pragma unroll
    for (int i = 0; i < 4; ++i) {
#pragma unroll
      for (int j = 0; j < 4; ++j) {
#pragma unroll
        for (int jj = 0; jj < 4; ++jj) {
          int gm = m0 + wr + i * 16 + fq * 4 + jj;
          int gn = n0 + wc + j * 16 + fr;
          float v = acc[i][j][jj] + bias[gn];
          if (EPI == 1) {
            size_t idx = (size_t)gm * 512 + gn;
            outf[idx] = v + resid[idx];
          } else if (EPI == 2) {
            outb[(size_t)gm * (size_t)N + gn] = f2b(fast_gelu(v));
          } else {
            size_t idx = (size_t)gm * 512 + gn;
            outf[idx] = v + resid[idx];               // f32 store to d_out
          }
        }
      }
    }
  }
}

// ---------------- Attention pass 1: per-chunk kv partial P_c = (k*kdec)^T @ v ----------------
// grid 1024 = bh*32 + c. Output P[bid] as f32 64x64 in (e, dd) layout.
__global__ __launch_bounds__(256) void attn_kv_kernel(
    const u16* __restrict__ k, const u16* __restrict__ v, float* __restrict__ P) {
  constexpr int LT = 136;
  __shared__ __align__(16) u16 kT_s[64 * LT];
  __shared__ __align__(16) u16 vT_s[64 * LT];
  __shared__ float kdec[128];
  int bid = blockIdx.x;
  int bh = bid >> 5;
  float sl = exp2f(-(float)((bh & 7) + 1));
  int t = threadIdx.x, lane = t & 63, wid = t >> 6;
  for (int i = t; i < 128; i += 256) kdec[i] = expf(-sl * (float)(128 - i));
  const u16* kb = k + (size_t)bid * 8192;
  const u16* vb = v + (size_t)bid * 8192;
  __syncthreads();
  int fr = lane & 15, fk = (lane >> 4) * 8, fq = lane >> 4;
#pragma unroll
  for (int i = 0; i < 16; ++i) {
    int seg = t + i * 256;
    int j = seg >> 5, dd = (seg & 31) * 2;
    unsigned int kp = *(const unsigned int*)&kb[(size_t)j * 64 + dd];
    float kd = kdec[j];
    kT_s[dd * LT + j] = f2b(b2f((u16)(kp & 0xFFFFu)) * kd);
    kT_s[(dd + 1) * LT + j] = f2b(b2f((u16)(kp >> 16)) * kd);
    unsigned int vp = *(const unsigned int*)&vb[(size_t)j * 64 + dd];
    vT_s[dd * LT + j] = (u16)(vp & 0xFFFFu);
    vT_s[(dd + 1) * LT + j] = (u16)(vp >> 16);
  }
  __syncthreads();
  f32x4 accKV[4] = {};
#pragma unroll
  for (int kk = 0; kk < 4; ++kk) {
    bf16x8 akt = *(const bf16x8*)&kT_s[(wid * 16 + fr) * LT + kk * 32 + fk];
#pragma unroll
    for (int j = 0; j < 4; ++j) {
      bf16x8 bvt = *(const bf16x8*)&vT_s[(j * 16 + fr) * LT + kk * 32 + fk];
      accKV[j] = __builtin_amdgcn_mfma_f32_16x16x32_bf16(akt, bvt, accKV[j], 0, 0, 0);
    }
  }
  // park P^T (e, dd) into f32 LDS (overlay kT_s), stride 68 to spread banks
  float* PT = (float*)kT_s;      // 64*68*4 = 17408 B <= kT_s 34816 B
  __syncthreads();
#pragma unroll
  for (int j = 0; j < 4; ++j)
#pragma unroll
    for (int jj = 0; jj < 4; ++jj) {
      int dd = wid * 16 + fq * 4 + jj;
      int e = j * 16 + fr;
      PT[e * 68 + dd] = accKV[j][jj];
    }
  __syncthreads();
  float* Pg = P + (size_t)bid * 4096;
  int e = t >> 2, d0 = (t & 3) * 16;
#pragma unroll
  for (int g = 0; g < 4; ++g) {
    f32x4 val = *(const f32x4*)&PT[e * 68 + d0 + g * 4];
    *(f32x4*)&Pg[(size_t)e * 64 + d0 + g * 4] = val;
  }
}

// ---------------- Attention pass 2: scan kv state; emit pre-chunk state as bf16 (e,d) ----------------
__global__ __launch_bounds__(256) void attn_scan_kernel(
    const float* __restrict__ P, u16* __restrict__ kvst) {
  int bh = blockIdx.x, t = threadIdx.x;
  float sl = exp2f(-(float)((bh & 7) + 1));
  float cdec = expf(-sl * 128.0f);
  float kv[16];
#pragma unroll
  for (int i = 0; i < 16; ++i) kv[i] = 0.f;
  for (int c = 0; c < 32; ++c) {
    size_t off = (((size_t)bh * 32 + c) * 4096) + (size_t)t * 16;
    union { u16 st[16]; uint4 v4[4]; } u;
#pragma unroll
    for (int i = 0; i < 16; ++i) u.st[i] = f2b(kv[i]);
    *(uint4*)&kvst[off] = u.v4[0];
    *(uint4*)&kvst[off + 8] = u.v4[1];
#pragma unroll
    for (int g = 0; g < 4; ++g) {
      f32x4 p = *(const f32x4*)&P[off + g * 4];
#pragma unroll
      for (int e = 0; e < 4; ++e) kv[g * 4 + e] = cdec * kv[g * 4 + e] + p[e];
    }
  }
}

// ---------------- Attention pass 3: out_c = masked(QK^T)@V + qdec*(Q@kv_state) ----------------
__global__ __launch_bounds__(256) void attn_out_kernel(
    const u16* __restrict__ q, const u16* __restrict__ k, const u16* __restrict__ v,
    const u16* __restrict__ kvst, u16* __restrict__ o) {
  constexpr int LQ = 72, LT = 136, LS = 136, LKV = 72;
  __shared__ __align__(16) u16 sm[31744];
  u16* q_s  = sm;              // 128*72
  u16* k_s  = sm + 9216;       // 128*72
  u16* vT_s = sm + 18432;      // 64*136
  u16* kvT_s = sm + 27136;     // 64*72
  u16* S_s  = sm;              // 128*136 overlays q_s+k_s (dead after S/inter MFMA)
  __shared__ float rowf[128], colf[128];
  int bid = blockIdx.x;
  int bh = bid >> 5;
  float sl = exp2f(-(float)((bh & 7) + 1));
  int t = threadIdx.x, lane = t & 63, wid = t >> 6;
  for (int i = t; i < 128; i += 256) {
    rowf[i] = expf(-sl * i);
    colf[i] = expf(sl * i);
  }
  const u16* qb = q + (size_t)bid * 8192;
  const u16* kb = k + (size_t)bid * 8192;
  const u16* vb = v + (size_t)bid * 8192;
  const u16* kvb = kvst + (size_t)bid * 4096;
  u16* ob = o + (size_t)bid * 8192;
  int fr = lane & 15, fk = (lane >> 4) * 8, fq = lane >> 4;
#pragma unroll
  for (int i = 0; i < 4; ++i) {        // q,k row-major
    int seg = t + i * 256;
    int r = seg >> 3, cc = (seg & 7) * 8;
    *(uint4*)&q_s[r * LQ + cc] = *(const uint4*)&qb[(size_t)r * 64 + cc];
    *(uint4*)&k_s[r * LQ + cc] = *(const uint4*)&kb[(size_t)r * 64 + cc];
  }
#pragma unroll
  for (int i = 0; i < 16; ++i) {       // vT transpose
    int seg = t + i * 256;
    int j = seg >> 5, dd = (seg & 31) * 2;
    unsigned int vp = *(const unsigned int*)&vb[(size_t)j * 64 + dd];
    vT_s[dd * LT + j] = (u16)(vp & 0xFFFFu);
    vT_s[(dd + 1) * LT + j] = (u16)(vp >> 16);
  }
#pragma unroll
  for (int i = 0; i < 2; ++i) {        // kv state straight copy (already (e,d))
    int seg = t + i * 256;
    int e = seg >> 3, dd = (seg & 7) * 8;
    *(uint4*)&kvT_s[e * LKV + dd] = *(const uint4*)&kvb[(size_t)e * 64 + dd];
  }
  __syncthreads();
  // S = Q K^T and inter = Q @ kv  (wave owns q-rows [wid*32, +32))
  f32x4 accS[2][8] = {};
  f32x4 accI[2][4] = {};
#pragma unroll
  for (int kk = 0; kk < 2; ++kk) {
    bf16x8 aq0 = *(const bf16x8*)&q_s[(wid * 32 + fr) * LQ + kk * 32 + fk];
    bf16x8 aq1 = *(const bf16x8*)&q_s[(wid * 32 + 16 + fr) * LQ + kk * 32 + fk];
#pragma unroll
    for (int j = 0; j < 8; ++j) {
      bf16x8 bk = *(const bf16x8*)&k_s[(j * 16 + fr) * LQ + kk * 32 + fk];
      accS[0][j] = __builtin_amdgcn_mfma_f32_16x16x32_bf16(aq0, bk, accS[0][j], 0, 0, 0);
      accS[1][j] = __builtin_amdgcn_mfma_f32_16x16x32_bf16(aq1, bk, accS[1][j], 0, 0, 0);
    }
#pragma unroll
    for (int j = 0; j < 4; ++j) {
      bf16x8 bkv = *(const bf16x8*)&kvT_s[(j * 16 + fr) * LKV + kk * 32 + fk];
      accI[0][j] = __builtin_amdgcn_mfma_f32_16x16x32_bf16(aq0, bkv, accI[0][j], 0, 0, 0);
      accI[1][j] = __builtin_amdgcn_mfma_f32_16x16x32_bf16(aq1, bkv, accI[1][j], 0, 0, 0);
    }
  }
  __syncthreads();   // q_s,k_s now dead -> S_s region reusable
#pragma unroll
  for (int i = 0; i < 2; ++i)
#pragma unroll
    for (int j = 0; j < 8; ++j)
#pragma unroll
      for (int jj = 0; jj < 4; ++jj) {
        int si = wid * 32 + i * 16 + fq * 4 + jj;
        int sj = j * 16 + fr;
        float val = (si >= sj) ? accS[i][j][jj] * rowf[si] * colf[sj] : 0.0f;
        S_s[si * LS + sj] = f2b(val);
      }
  __syncthreads();
  // intra = S' @ V
  f32x4 accO[2][4] = {};
#pragma unroll
  for (int kk = 0; kk < 4; ++kk) {
    bf16x8 as0 = *(const bf16x8*)&S_s[(wid * 32 + fr) * LS + kk * 32 + fk];
    bf16x8 as1 = *(const bf16x8*)&S_s[(wid * 32 + 16 + fr) * LS + kk * 32 + fk];
#pragma unroll
    for (int j = 0; j < 4; ++j) {
      bf16x8 bvt = *(const bf16x8*)&vT_s[(j * 16 + fr) * LT + kk * 32 + fk];
      accO[0][j] = __builtin_amdgcn_mfma_f32_16x16x32_bf16(as0, bvt, accO[0][j], 0, 0, 0);
      accO[1][j] = __builtin_amdgcn_mfma_f32_16x16x32_bf16(as1, bvt, accO[1][j], 0, 0, 0);
    }
  }
#pragma unroll
  for (int i = 0; i < 2; ++i)
#pragma unroll
    for (int j = 0; j < 4; ++j)
#pragma unroll
      for (int jj = 0; jj < 4; ++jj) {
        int li = wid * 32 + i * 16 + fq * 4 + jj;
        int e = j * 16 + fr;
        float val = accO[i][j][jj] + rowf[li] * accI[i][j][jj];
        ob[(size_t)li * 64 + e] = f2b(val);
      }
}

extern "C" void kernel_launch(void* const* d_in, const int* in_sizes, int n_in,
                              void* d_out, int out_size, void* d_ws, size_t ws_size,
                              hipStream_t stream) {
  const float* x      = (const float*)d_in[0];
  const float* ln1_w  = (const float*)d_in[1];
  const float* ln1_b  = (const float*)d_in[2];
  const float* rel    = (const float*)d_in[3];
  const float* qkv_w  = (const float*)d_in[4];
  const float* qkv_b  = (const float*)d_in[5];
  const float* gq     = (const float*)d_in[6];
  const float* gk     = (const float*)d_in[7];
  const float* proj_w = (const float*)d_in[8];
  const float* proj_b = (const float*)d_in[9];
  const float* ln2_w  = (const float*)d_in[10];
  const float* ln2_b  = (const float*)d_in[11];
  const float* fc1_w  = (const float*)d_in[12];
  const float* fc1_b  = (const float*)d_in[13];
  const float* fc2_w  = (const float*)d_in[14];
  const float* fc2_b  = (const float*)d_in[15];

  char* ws = (char*)d_ws;
  size_t off = 0;
  auto alloc = [&](size_t bytes) { char* p = ws + off; off += (bytes + 255) & ~(size_t)255; return p; };
  u16* w_qkv  = (u16*)alloc((size_t)1536 * 512 * 2);
  u16* w_proj = (u16*)alloc((size_t)512 * 512 * 2);
  u16* w_fc1  = (u16*)alloc((size_t)2048 * 512 * 2);
  u16* w_fc2  = (u16*)alloc((size_t)512 * 2048 * 2);
  u16* h_buf  = (u16*)alloc((size_t)16384 * 512 * 2);   // ln1 out; reused for ln2 out
  u16* q_buf  = (u16*)alloc((size_t)8388608 * 2);
  u16* k_buf  = (u16*)alloc((size_t)8388608 * 2);
  u16* v_buf  = (u16*)alloc((size_t)8388608 * 2);
  u16* o_buf  = (u16*)alloc((size_t)8388608 * 2);
  float* x2   = (float*)alloc((size_t)8388608 * 4);
  u16* mid    = q_buf;   // 16384x2048 bf16 overlays q..o (dead after attention/proj)
  // attention scratch overlays x2 (x2 written only after attention):
  float* P_glob  = x2;                       // 1024*4096 f32 = 16.8 MB
  u16*   kv_state = (u16*)(x2 + 4194304);    // 1024*4096 bf16 = 8.4 MB

  conv_f2b_kernel<<<512, 256, 0, stream>>>(qkv_w, w_qkv, 1536 * 512);
  conv_f2b_kernel<<<512, 256, 0, stream>>>(proj_w, w_proj, 512 * 512);
  conv_f2b_kernel<<<512, 256, 0, stream>>>(fc1_w, w_fc1, 2048 * 512);
  conv_f2b_kernel<<<512, 256, 0, stream>>>(fc2_w, w_fc2, 512 * 2048);

  ln_kernel<1><<<16384, 256, 0, stream>>>(x, ln1_w, ln1_b, rel, h_buf);

  gemm_bt_kernel<0><<<1536, 256, 0, stream>>>(h_buf, w_qkv, qkv_b, 16384, 1536, 512, 12,
      nullptr, nullptr, q_buf, k_buf, v_buf, nullptr, gq, gk);

  attn_kv_kernel<<<1024, 256, 0, stream>>>(k_buf, v_buf, P_glob);
  attn_scan_kernel<<<32, 256, 0, stream>>>(P_glob, kv_state);
  attn_out_kernel<<<1024, 256, 0, stream>>>(q_buf, k_buf, v_buf, kv_state, o_buf);

  gemm_bt_kernel<1><<<512, 256, 0, stream>>>(o_buf, w_proj, proj_b, 16384, 512, 512, 4,
      x, nullptr, nullptr, nullptr, nullptr, x2, nullptr, nullptr);

  ln_kernel<0><<<16384, 256, 0, stream>>>(x2, ln2_w, ln2_b, nullptr, h_buf);

  gemm_bt_kernel<2><<<2048, 256, 0, stream>>>(h_buf, w_fc1, fc1_b, 16384, 2048, 512, 16,
      nullptr, mid, nullptr, nullptr, nullptr, nullptr, nullptr, nullptr);

  gemm_bt_kernel<3><<<512, 256, 0, stream>>>(mid, w_fc2, fc2_b, 16384, 512, 2048, 4,
      x2, nullptr, nullptr, nullptr, nullptr, (float*)d_out, nullptr, nullptr);

  (void)in_sizes; (void)n_in; (void)out_size; (void)ws_size;
}

// Round 14
// 271.636 us; speedup vs baseline: 7.7143x; 1.0307x over previous
//
#include <hip/hip_runtime.h>
#include <math.h>

typedef unsigned short u16;
typedef __bf16 bf16x8 __attribute__((ext_vector_type(8)));
typedef float f32x4 __attribute__((ext_vector_type(4)));

#define DEVI static __device__ __forceinline__

DEVI float b2f(u16 u) { union { unsigned int i; float f; } w; w.i = ((unsigned int)u) << 16; return w.f; }
DEVI u16 f2b(float f) {
  union { float f; unsigned int i; } w; w.f = f;
  unsigned int r = (w.i + 0x7FFFu + ((w.i >> 16) & 1u)) >> 16;
  return (u16)r;
}
DEVI u16 cvt_bf16(float f) { __bf16 h = (__bf16)f; union { __bf16 h; u16 u; } w; w.h = h; return w.u; }

// tanh-GELU: x * rcp(1 + exp2(-x*(c1 + c2*x^2))), max |err| vs exact ~3e-4.
DEVI float fast_gelu(float v) {
  float x2 = v * v;
  float p = fmaf(0.10294357f, x2, 2.30215855f);
  float ex = exp2f(-v * p);
  return v * __builtin_amdgcn_rcpf(1.0f + ex);
}

// ---------------- f32 -> bf16 conversion for all 4 weight mats in one launch ----------------
__global__ void conv4_kernel(const float* __restrict__ s0, u16* __restrict__ d0, int n0,
                             const float* __restrict__ s1, u16* __restrict__ d1, int n1,
                             const float* __restrict__ s2, u16* __restrict__ d2, int n2,
                             const float* __restrict__ s3, u16* __restrict__ d3, int n3) {
  int i = blockIdx.x * 256 + threadIdx.x;
  int st = gridDim.x * 256;
  int tot = n0 + n1 + n2 + n3;
  for (; i < tot; i += st) {
    int j = i;
    if (j < n0) { d0[j] = f2b(s0[j]); continue; }
    j -= n0;
    if (j < n1) { d1[j] = f2b(s1[j]); continue; }
    j -= n1;
    if (j < n2) { d2[j] = f2b(s2[j]); continue; }
    j -= n2;
    d3[j] = f2b(s3[j]);
  }
}

// ---------------- LayerNorm (+optional rel_bias), f32 in -> bf16 out ----------------
template<int ADD_REL>
__global__ __launch_bounds__(256) void ln_kernel(
    const float* __restrict__ x, const float* __restrict__ w, const float* __restrict__ bb,
    const float* __restrict__ rel, u16* __restrict__ out) {
  int row = blockIdx.x;            // 0..16383 = b*4096 + l
  int t = threadIdx.x;             // 256
  const float* xr = x + (size_t)row * 512;
  float v0 = xr[t], v1 = xr[t + 256];
  float s = v0 + v1, ss = v0 * v0 + v1 * v1;
#pragma unroll
  for (int o = 32; o > 0; o >>= 1) { s += __shfl_down(s, o); ss += __shfl_down(ss, o); }
  __shared__ float rs[4], rss[4];
  int lane = t & 63, wid = t >> 6;
  if (lane == 0) { rs[wid] = s; rss[wid] = ss; }
  __syncthreads();
  s = rs[0] + rs[1] + rs[2] + rs[3];
  ss = rss[0] + rss[1] + rss[2] + rss[3];
  float mu = s * (1.0f / 512.0f);
  float inv = rsqrtf(ss * (1.0f / 512.0f) - mu * mu + 1e-5f);
  float o0 = (v0 - mu) * inv * w[t] + bb[t];
  float o1 = (v1 - mu) * inv * w[t + 256] + bb[t + 256];
  if (ADD_REL) {
    const float* rr = rel + (size_t)(row & 4095) * 512;
    o0 += rr[t]; o1 += rr[t + 256];
  }
  u16* orow = out + (size_t)row * 512;
  orow[t] = f2b(o0);
  orow[t + 256] = f2b(o1);
}

// ---------------- GEMM: C[M,N] = A[M,K] @ W[N,K]^T + bias, bf16 MFMA ----------------
// 2-phase dbuf K-loop (global_load_lds 16B, linear LDS) + LDS-repacked vectorized epilogue.
// Park stride LP=68 f32 (272B rows, 16B-aligned). Signature:
//   (A, W, bias, M, N, K, NBN, resid, outb, q_out, k_out, v_out, outf, gq, gk)
// EPI: 0 = qkv scatter + fused RMS on q/k (q_out/k_out/v_out)
//      1 = +residual -> f32 out (resid, outf)
//      2 = gelu -> bf16 out (outb)   ** outb MUST be non-null — round-10..13 crash
//          was outb=nullptr from an argument-order slip at this call site **
template<int EPI>
__global__ __launch_bounds__(256) void gemm_bt_kernel(
    const u16* __restrict__ A, const u16* __restrict__ W,
    const float* __restrict__ bias, int M, int N, int K, int NBN,
    const float* __restrict__ resid, u16* __restrict__ outb,
    u16* __restrict__ q_out, u16* __restrict__ k_out, u16* __restrict__ v_out,
    float* __restrict__ outf, const float* __restrict__ gq, const float* __restrict__ gk) {
  __shared__ __align__(16) u16 sbuf[16384];    // [2]A(8KB ea) + [2]B; reused as f32 park
  int nwg = gridDim.x, wg = blockIdx.x;
  int wgs = (wg & 7) * (nwg >> 3) + (wg >> 3);     // XCD chunking (bijective: nwg%8==0)
  int bn = wgs % NBN, bm = wgs / NBN;
  int m0 = bm * 128, n0 = bn * 128;
  int t = threadIdx.x, lane = t & 63, wid = t >> 6;
  int wr = (wid >> 1) * 64, wc = (wid & 1) * 64;    // wave -> 64x64 quadrant
  int fr = lane & 15, fk = (lane >> 4) * 8;
  // staging: wave wid stages rows [wid*32, wid*32+32); chunk = 16 rows = 1KB.
  int srow = wid * 32 + (lane >> 2);
  int scol = (lane & 3) * 8;
  const u16* gA = A + (size_t)(m0 + srow) * K + scol;
  const u16* gB = W + (size_t)(n0 + srow) * K + scol;
  f32x4 acc[4][4] = {};
  auto AS = [&](int sel) { return &sbuf[sel * 4096]; };
  auto BS = [&](int sel) { return &sbuf[8192 + sel * 4096]; };
  auto STAGE = [&](int sel, int k0) {
    u16* lA = AS(sel) + wid * 1024;            // wave-uniform LDS base
    u16* lB = BS(sel) + wid * 1024;
    __builtin_amdgcn_global_load_lds(gA + k0,          lA,       16, 0, 0);
    __builtin_amdgcn_global_load_lds(gA + k0 + 16 * K, lA + 512, 16, 0, 0);
    __builtin_amdgcn_global_load_lds(gB + k0,          lB,       16, 0, 0);
    __builtin_amdgcn_global_load_lds(gB + k0 + 16 * K, lB + 512, 16, 0, 0);
  };
  STAGE(0, 0);
  asm volatile("s_waitcnt vmcnt(0)" ::: "memory");
  __builtin_amdgcn_s_barrier();
  int cur = 0;
  for (int k0 = 0; k0 < K; k0 += 32) {
    if (k0 + 32 < K) STAGE(cur ^ 1, k0 + 32);  // prefetch next tile (uniform branch)
    bf16x8 af[4], bfr[4];
#pragma unroll
    for (int i = 0; i < 4; ++i) af[i] = *(const bf16x8*)&AS(cur)[(wr + i * 16 + fr) * 32 + fk];
#pragma unroll
    for (int j = 0; j < 4; ++j) bfr[j] = *(const bf16x8*)&BS(cur)[(wc + j * 16 + fr) * 32 + fk];
#pragma unroll
    for (int i = 0; i < 4; ++i)
#pragma unroll
      for (int j = 0; j < 4; ++j)
        acc[i][j] = __builtin_amdgcn_mfma_f32_16x16x32_bf16(af[i], bfr[j], acc[i][j], 0, 0, 0);
    asm volatile("s_waitcnt vmcnt(0)" ::: "memory");   // prefetch landed
    __builtin_amdgcn_s_barrier();                      // all waves done reading cur
    cur ^= 1;
  }
  // ---- Epilogue: park f32 in wave-private LDS, read back lane-contiguous ----
  // (Final K-iteration barrier: all waves' frag ds_reads retired before any park write.)
  int fq = lane >> 4;
  constexpr int LP = 68;                       // f32 row stride: 272B, 16B-aligned
  float* lbuf = (float*)sbuf + wid * 2048;     // 8KB per wave; 16x68 f32 = 4352B used
  float bv[4];
#pragma unroll
  for (int j = 0; j < 4; ++j) bv[j] = bias[n0 + wc + j * 16 + fr];
  int rr = lane >> 2, c0 = (lane & 3) * 16;    // readback: row rr, cols c0..c0+15
  // EPI==0 per-quadrant constants
  int nb = n0 + wc;
  int which = nb >> 9, head = (nb >> 6) & 7;
  float ggv[16];
  if (EPI == 0 && which != 2) {
    const float* gg = (which == 0) ? gq : gk;
#pragma unroll
    for (int e = 0; e < 16; ++e) ggv[e] = gg[head * 64 + c0 + e];
  }
#pragma unroll
  for (int i = 0; i < 4; ++i) {
#pragma unroll
    for (int j = 0; j < 4; ++j)
#pragma unroll
      for (int jj = 0; jj < 4; ++jj)
        lbuf[(fq * 4 + jj) * LP + j * 16 + fr] = acc[i][j][jj] + bv[j];
    // same-wave ds_write -> ds_read; compiler orders via lgkmcnt
    float v[16];
#pragma unroll
    for (int g = 0; g < 4; ++g) {
      f32x4 r4 = *(const f32x4*)&lbuf[rr * LP + c0 + g * 4];
#pragma unroll
      for (int e = 0; e < 4; ++e) v[g * 4 + e] = r4[e];
    }
    int gm = m0 + wr + i * 16 + rr;
    if (EPI == 0) {
      u16* dst = (which == 0) ? q_out : (which == 1) ? k_out : v_out;
      int b = gm >> 12, l = gm & 4095;
      size_t rowbase = (((size_t)(b * 8 + head) * 4096) + l) * 64 + c0;
      union { u16 h[16]; uint4 q[2]; } pk;
      if (which == 2) {
#pragma unroll
        for (int e = 0; e < 16; ++e) pk.h[e] = cvt_bf16(v[e]);
      } else {
        float ssum = 0.f;
#pragma unroll
        for (int e = 0; e < 16; ++e) ssum += v[e] * v[e];
        ssum += __shfl_xor(ssum, 1);
        ssum += __shfl_xor(ssum, 2);               // row-sum within 4-lane group
        float inv = 8.0f / fmaxf(sqrtf(ssum), 1e-12f);
#pragma unroll
        for (int e = 0; e < 16; ++e) pk.h[e] = cvt_bf16(v[e] * inv * ggv[e]);
      }
      *(uint4*)&dst[rowbase] = pk.q[0];
      *(uint4*)&dst[rowbase + 8] = pk.q[1];
    } else if (EPI == 1) {
      size_t idx = (size_t)gm * 512 + n0 + wc + c0;
#pragma unroll
      for (int g = 0; g < 4; ++g) {
        f32x4 r = *(const f32x4*)&resid[idx + g * 4];
        f32x4 o;
#pragma unroll
        for (int e = 0; e < 4; ++e) o[e] = v[g * 4 + e] + r[e];
        *(f32x4*)&outf[idx + g * 4] = o;
      }
    } else {  // EPI == 2: gelu -> bf16
      union { u16 h[16]; uint4 q[2]; } pk;
#pragma unroll
      for (int e = 0; e < 16; ++e) pk.h[e] = cvt_bf16(fast_gelu(v[e]));
      size_t idx = (size_t)gm * (size_t)N + n0 + wc + c0;
      *(uint4*)&outb[idx] = pk.q[0];
      *(uint4*)&outb[idx + 8] = pk.q[1];
    }
  }
}

// ---------------- Attention pass 1: per-chunk kv partial P_c = (k*kdec)^T @ v ----------------
// grid 1024 = bh*32 + c. Output P[bid] as f32 64x64 in (e, dd) layout.
__global__ __launch_bounds__(256) void attn_kv_kernel(
    const u16* __restrict__ k, const u16* __restrict__ v, float* __restrict__ P) {
  constexpr int LT = 136;
  __shared__ __align__(16) u16 kT_s[64 * LT];
  __shared__ __align__(16) u16 vT_s[64 * LT];
  __shared__ float kdec[128];
  int bid = blockIdx.x;
  int bh = bid >> 5;
  float sl = exp2f(-(float)((bh & 7) + 1));
  int t = threadIdx.x, lane = t & 63, wid = t >> 6;
  for (int i = t; i < 128; i += 256) kdec[i] = expf(-sl * (float)(128 - i));
  const u16* kb = k + (size_t)bid * 8192;
  const u16* vb = v + (size_t)bid * 8192;
  __syncthreads();
  int fr = lane & 15, fk = (lane >> 4) * 8, fq = lane >> 4;
#pragma unroll
  for (int i = 0; i < 16; ++i) {
    int seg = t + i * 256;
    int j = seg >> 5, dd = (seg & 31) * 2;
    unsigned int kp = *(const unsigned int*)&kb[(size_t)j * 64 + dd];
    float kd = kdec[j];
    kT_s[dd * LT + j] = f2b(b2f((u16)(kp & 0xFFFFu)) * kd);
    kT_s[(dd + 1) * LT + j] = f2b(b2f((u16)(kp >> 16)) * kd);
    unsigned int vp = *(const unsigned int*)&vb[(size_t)j * 64 + dd];
    vT_s[dd * LT + j] = (u16)(vp & 0xFFFFu);
    vT_s[(dd + 1) * LT + j] = (u16)(vp >> 16);
  }
  __syncthreads();
  f32x4 accKV[4] = {};
#pragma unroll
  for (int kk = 0; kk < 4; ++kk) {
    bf16x8 akt = *(const bf16x8*)&kT_s[(wid * 16 + fr) * LT + kk * 32 + fk];
#pragma unroll
    for (int j = 0; j < 4; ++j) {
      bf16x8 bvt = *(const bf16x8*)&vT_s[(j * 16 + fr) * LT + kk * 32 + fk];
      accKV[j] = __builtin_amdgcn_mfma_f32_16x16x32_bf16(akt, bvt, accKV[j], 0, 0, 0);
    }
  }
  // park P^T (e, dd) into f32 LDS (overlay kT_s), stride 68 to spread banks
  float* PT = (float*)kT_s;      // 64*68*4 = 17408 B <= kT_s 34816 B
  __syncthreads();
#pragma unroll
  for (int j = 0; j < 4; ++j)
#pragma unroll
    for (int jj = 0; jj < 4; ++jj) {
      int dd = wid * 16 + fq * 4 + jj;
      int e = j * 16 + fr;
      PT[e * 68 + dd] = accKV[j][jj];
    }
  __syncthreads();
  float* Pg = P + (size_t)bid * 4096;
  int e = t >> 2, d0 = (t & 3) * 16;
#pragma unroll
  for (int g = 0; g < 4; ++g) {
    f32x4 val = *(const f32x4*)&PT[e * 68 + d0 + g * 4];
    *(f32x4*)&Pg[(size_t)e * 64 + d0 + g * 4] = val;
  }
}

// ---------------- Attention pass 2: scan kv state; emit pre-chunk state as bf16 (e,d) ----------------
__global__ __launch_bounds__(256) void attn_scan_kernel(
    const float* __restrict__ P, u16* __restrict__ kvst) {
  int bh = blockIdx.x, t = threadIdx.x;
  float sl = exp2f(-(float)((bh & 7) + 1));
  float cdec = expf(-sl * 128.0f);
  float kv[16];
#pragma unroll
  for (int i = 0; i < 16; ++i) kv[i] = 0.f;
  for (int c = 0; c < 32; ++c) {
    size_t off = (((size_t)bh * 32 + c) * 4096) + (size_t)t * 16;
    union { u16 st[16]; uint4 v4[4]; } u;
#pragma unroll
    for (int i = 0; i < 16; ++i) u.st[i] = f2b(kv[i]);
    *(uint4*)&kvst[off] = u.v4[0];
    *(uint4*)&kvst[off + 8] = u.v4[1];
#pragma unroll
    for (int g = 0; g < 4; ++g) {
      f32x4 p = *(const f32x4*)&P[off + g * 4];
#pragma unroll
      for (int e = 0; e < 4; ++e) kv[g * 4 + e] = cdec * kv[g * 4 + e] + p[e];
    }
  }
}

// ---------------- Attention pass 3: out_c = masked(QK^T)@V + qdec*(Q@kv_state) ----------------
__global__ __launch_bounds__(256) void attn_out_kernel(
    const u16* __restrict__ q, const u16* __restrict__ k, const u16* __restrict__ v,
    const u16* __restrict__ kvst, u16* __restrict__ o) {
  constexpr int LQ = 72, LT = 136, LS = 136, LKV = 72;
  __shared__ __align__(16) u16 sm[31744];
  u16* q_s  = sm;              // 128*72
  u16* k_s  = sm + 9216;       // 128*72
  u16* vT_s = sm + 18432;      // 64*136
  u16* kvT_s = sm + 27136;     // 64*72
  u16* S_s  = sm;              // 128*136 overlays q_s+k_s (dead after S/inter MFMA)
  __shared__ float rowf[128], colf[128];
  int bid = blockIdx.x;
  int bh = bid >> 5;
  float sl = exp2f(-(float)((bh & 7) + 1));
  int t = threadIdx.x, lane = t & 63, wid = t >> 6;
  for (int i = t; i < 128; i += 256) {
    rowf[i] = expf(-sl * i);
    colf[i] = expf(sl * i);
  }
  const u16* qb = q + (size_t)bid * 8192;
  const u16* kb = k + (size_t)bid * 8192;
  const u16* vb = v + (size_t)bid * 8192;
  const u16* kvb = kvst + (size_t)bid * 4096;
  u16* ob = o + (size_t)bid * 8192;
  int fr = lane & 15, fk = (lane >> 4) * 8, fq = lane >> 4;
#pragma unroll
  for (int i = 0; i < 4; ++i) {        // q,k row-major
    int seg = t + i * 256;
    int r = seg >> 3, cc = (seg & 7) * 8;
    *(uint4*)&q_s[r * LQ + cc] = *(const uint4*)&qb[(size_t)r * 64 + cc];
    *(uint4*)&k_s[r * LQ + cc] = *(const uint4*)&kb[(size_t)r * 64 + cc];
  }
#pragma unroll
  for (int i = 0; i < 16; ++i) {       // vT transpose
    int seg = t + i * 256;
    int j = seg >> 5, dd = (seg & 31) * 2;
    unsigned int vp = *(const unsigned int*)&vb[(size_t)j * 64 + dd];
    vT_s[dd * LT + j] = (u16)(vp & 0xFFFFu);
    vT_s[(dd + 1) * LT + j] = (u16)(vp >> 16);
  }
#pragma unroll
  for (int i = 0; i < 2; ++i) {        // kv state straight copy (already (e,d))
    int seg = t + i * 256;
    int e = seg >> 3, dd = (seg & 7) * 8;
    *(uint4*)&kvT_s[e * LKV + dd] = *(const uint4*)&kvb[(size_t)e * 64 + dd];
  }
  __syncthreads();
  // S = Q K^T and inter = Q @ kv  (wave owns q-rows [wid*32, +32))
  f32x4 accS[2][8] = {};
  f32x4 accI[2][4] = {};
#pragma unroll
  for (int kk = 0; kk < 2; ++kk) {
    bf16x8 aq0 = *(const bf16x8*)&q_s[(wid * 32 + fr) * LQ + kk * 32 + fk];
    bf16x8 aq1 = *(const bf16x8*)&q_s[(wid * 32 + 16 + fr) * LQ + kk * 32 + fk];
#pragma unroll
    for (int j = 0; j < 8; ++j) {
      bf16x8 bk = *(const bf16x8*)&k_s[(j * 16 + fr) * LQ + kk * 32 + fk];
      accS[0][j] = __builtin_amdgcn_mfma_f32_16x16x32_bf16(aq0, bk, accS[0][j], 0, 0, 0);
      accS[1][j] = __builtin_amdgcn_mfma_f32_16x16x32_bf16(aq1, bk, accS[1][j], 0, 0, 0);
    }
#pragma unroll
    for (int j = 0; j < 4; ++j) {
      bf16x8 bkv = *(const bf16x8*)&kvT_s[(j * 16 + fr) * LKV + kk * 32 + fk];
      accI[0][j] = __builtin_amdgcn_mfma_f32_16x16x32_bf16(aq0, bkv, accI[0][j], 0, 0, 0);
      accI[1][j] = __builtin_amdgcn_mfma_f32_16x16x32_bf16(aq1, bkv, accI[1][j], 0, 0, 0);
    }
  }
  __syncthreads();   // q_s,k_s now dead -> S_s region reusable
#pragma unroll
  for (int i = 0; i < 2; ++i)
#pragma unroll
    for (int j = 0; j < 8; ++j)
#pragma unroll
      for (int jj = 0; jj < 4; ++jj) {
        int si = wid * 32 + i * 16 + fq * 4 + jj;
        int sj = j * 16 + fr;
        float val = (si >= sj) ? accS[i][j][jj] * rowf[si] * colf[sj] : 0.0f;
        S_s[si * LS + sj] = f2b(val);
      }
  __syncthreads();
  // intra = S' @ V
  f32x4 accO[2][4] = {};
#pragma unroll
  for (int kk = 0; kk < 4; ++kk) {
    bf16x8 as0 = *(const bf16x8*)&S_s[(wid * 32 + fr) * LS + kk * 32 + fk];
    bf16x8 as1 = *(const bf16x8*)&S_s[(wid * 32 + 16 + fr) * LS + kk * 32 + fk];
#pragma unroll
    for (int j = 0; j < 4; ++j) {
      bf16x8 bvt = *(const bf16x8*)&vT_s[(j * 16 + fr) * LT + kk * 32 + fk];
      accO[0][j] = __builtin_amdgcn_mfma_f32_16x16x32_bf16(as0, bvt, accO[0][j], 0, 0, 0);
      accO[1][j] = __builtin_amdgcn_mfma_f32_16x16x32_bf16(as1, bvt, accO[1][j], 0, 0, 0);
    }
  }
#pragma unroll
  for (int i = 0; i < 2; ++i)
#pragma unroll
    for (int j = 0; j < 4; ++j)
#pragma unroll
      for (int jj = 0; jj < 4; ++jj) {
        int li = wid * 32 + i * 16 + fq * 4 + jj;
        int e = j * 16 + fr;
        float val = accO[i][j][jj] + rowf[li] * accI[i][j][jj];
        ob[(size_t)li * 64 + e] = f2b(val);
      }
}

extern "C" void kernel_launch(void* const* d_in, const int* in_sizes, int n_in,
                              void* d_out, int out_size, void* d_ws, size_t ws_size,
                              hipStream_t stream) {
  const float* x      = (const float*)d_in[0];
  const float* ln1_w  = (const float*)d_in[1];
  const float* ln1_b  = (const float*)d_in[2];
  const float* rel    = (const float*)d_in[3];
  const float* qkv_w  = (const float*)d_in[4];
  const float* qkv_b  = (const float*)d_in[5];
  const float* gq     = (const float*)d_in[6];
  const float* gk     = (const float*)d_in[7];
  const float* proj_w = (const float*)d_in[8];
  const float* proj_b = (const float*)d_in[9];
  const float* ln2_w  = (const float*)d_in[10];
  const float* ln2_b  = (const float*)d_in[11];
  const float* fc1_w  = (const float*)d_in[12];
  const float* fc1_b  = (const float*)d_in[13];
  const float* fc2_w  = (const float*)d_in[14];
  const float* fc2_b  = (const float*)d_in[15];

  char* ws = (char*)d_ws;
  size_t off = 0;
  auto alloc = [&](size_t bytes) { char* p = ws + off; off += (bytes + 255) & ~(size_t)255; return p; };
  u16* w_qkv  = (u16*)alloc((size_t)1536 * 512 * 2);
  u16* w_proj = (u16*)alloc((size_t)512 * 512 * 2);
  u16* w_fc1  = (u16*)alloc((size_t)2048 * 512 * 2);
  u16* w_fc2  = (u16*)alloc((size_t)512 * 2048 * 2);
  u16* h_buf  = (u16*)alloc((size_t)16384 * 512 * 2);   // ln1 out; reused for ln2 out
  u16* q_buf  = (u16*)alloc((size_t)8388608 * 2);
  u16* k_buf  = (u16*)alloc((size_t)8388608 * 2);
  u16* v_buf  = (u16*)alloc((size_t)8388608 * 2);
  u16* o_buf  = (u16*)alloc((size_t)8388608 * 2);
  float* x2   = (float*)alloc((size_t)8388608 * 4);
  u16* mid    = q_buf;   // 16384x2048 bf16 overlays q..o (dead after attention/proj)
  // attention scratch overlays x2 (x2 written only after attention):
  float* P_glob  = x2;                       // 1024*4096 f32 = 16.8 MB
  u16*   kv_state = (u16*)(x2 + 4194304);    // 1024*4096 bf16 = 8.4 MB

  conv4_kernel<<<1024, 256, 0, stream>>>(qkv_w, w_qkv, 1536 * 512,
                                         proj_w, w_proj, 512 * 512,
                                         fc1_w, w_fc1, 2048 * 512,
                                         fc2_w, w_fc2, 512 * 2048);

  ln_kernel<1><<<16384, 256, 0, stream>>>(x, ln1_w, ln1_b, rel, h_buf);

  // (A, W, bias, M, N, K, NBN, resid, outb, q_out, k_out, v_out, outf, gq, gk)
  gemm_bt_kernel<0><<<1536, 256, 0, stream>>>(h_buf, w_qkv, qkv_b, 16384, 1536, 512, 12,
      /*resid*/nullptr, /*outb*/nullptr, /*q*/q_buf, /*k*/k_buf, /*v*/v_buf,
      /*outf*/nullptr, gq, gk);

  attn_kv_kernel<<<1024, 256, 0, stream>>>(k_buf, v_buf, P_glob);
  attn_scan_kernel<<<32, 256, 0, stream>>>(P_glob, kv_state);
  attn_out_kernel<<<1024, 256, 0, stream>>>(q_buf, k_buf, v_buf, kv_state, o_buf);

  gemm_bt_kernel<1><<<512, 256, 0, stream>>>(o_buf, w_proj, proj_b, 16384, 512, 512, 4,
      /*resid*/x, /*outb*/nullptr, nullptr, nullptr, nullptr, /*outf*/x2, nullptr, nullptr);

  ln_kernel<0><<<16384, 256, 0, stream>>>(x2, ln2_w, ln2_b, nullptr, h_buf);

  gemm_bt_kernel<2><<<2048, 256, 0, stream>>>(h_buf, w_fc1, fc1_b, 16384, 2048, 512, 16,
      /*resid*/nullptr, /*outb*/mid, nullptr, nullptr, nullptr, /*outf*/nullptr, nullptr, nullptr);

  gemm_bt_kernel<1><<<512, 256, 0, stream>>>(mid, w_fc2, fc2_b, 16384, 512, 2048, 4,
      /*resid*/x2, /*outb*/nullptr, nullptr, nullptr, nullptr, /*outf*/(float*)d_out, nullptr, nullptr);

  (void)in_sizes; (void)n_in; (void)out_size; (void)ws_size;
}

// Round 15
// 265.756 us; speedup vs baseline: 7.8850x; 1.0221x over previous
//
#include <hip/hip_runtime.h>
#include <math.h>

typedef unsigned short u16;
typedef __bf16 bf16x8 __attribute__((ext_vector_type(8)));
typedef float f32x4 __attribute__((ext_vector_type(4)));

#define DEVI static __device__ __forceinline__

DEVI float b2f(u16 u) { union { unsigned int i; float f; } w; w.i = ((unsigned int)u) << 16; return w.f; }
DEVI u16 f2b(float f) {
  union { float f; unsigned int i; } w; w.f = f;
  unsigned int r = (w.i + 0x7FFFu + ((w.i >> 16) & 1u)) >> 16;
  return (u16)r;
}
DEVI u16 cvt_bf16(float f) { __bf16 h = (__bf16)f; union { __bf16 h; u16 u; } w; w.h = h; return w.u; }

// tanh-GELU: x * rcp(1 + exp2(-x*(c1 + c2*x^2))), max |err| vs exact ~3e-4.
DEVI float fast_gelu(float v) {
  float x2 = v * v;
  float p = fmaf(0.10294357f, x2, 2.30215855f);
  float ex = exp2f(-v * p);
  return v * __builtin_amdgcn_rcpf(1.0f + ex);
}

// ---------------- f32 -> bf16 conversion for all 4 weight mats in one launch ----------------
__global__ void conv4_kernel(const float* __restrict__ s0, u16* __restrict__ d0, int n0,
                             const float* __restrict__ s1, u16* __restrict__ d1, int n1,
                             const float* __restrict__ s2, u16* __restrict__ d2, int n2,
                             const float* __restrict__ s3, u16* __restrict__ d3, int n3) {
  int i = blockIdx.x * 256 + threadIdx.x;
  int st = gridDim.x * 256;
  int tot = n0 + n1 + n2 + n3;
  for (; i < tot; i += st) {
    int j = i;
    if (j < n0) { d0[j] = f2b(s0[j]); continue; }
    j -= n0;
    if (j < n1) { d1[j] = f2b(s1[j]); continue; }
    j -= n1;
    if (j < n2) { d2[j] = f2b(s2[j]); continue; }
    j -= n2;
    d3[j] = f2b(s3[j]);
  }
}

// ---------------- LayerNorm (+optional rel_bias), f32 in -> bf16 out ----------------
template<int ADD_REL>
__global__ __launch_bounds__(256) void ln_kernel(
    const float* __restrict__ x, const float* __restrict__ w, const float* __restrict__ bb,
    const float* __restrict__ rel, u16* __restrict__ out) {
  int row = blockIdx.x;            // 0..16383 = b*4096 + l
  int t = threadIdx.x;             // 256
  const float* xr = x + (size_t)row * 512;
  float v0 = xr[t], v1 = xr[t + 256];
  float s = v0 + v1, ss = v0 * v0 + v1 * v1;
#pragma unroll
  for (int o = 32; o > 0; o >>= 1) { s += __shfl_down(s, o); ss += __shfl_down(ss, o); }
  __shared__ float rs[4], rss[4];
  int lane = t & 63, wid = t >> 6;
  if (lane == 0) { rs[wid] = s; rss[wid] = ss; }
  __syncthreads();
  s = rs[0] + rs[1] + rs[2] + rs[3];
  ss = rss[0] + rss[1] + rss[2] + rss[3];
  float mu = s * (1.0f / 512.0f);
  float inv = rsqrtf(ss * (1.0f / 512.0f) - mu * mu + 1e-5f);
  float o0 = (v0 - mu) * inv * w[t] + bb[t];
  float o1 = (v1 - mu) * inv * w[t + 256] + bb[t + 256];
  if (ADD_REL) {
    const float* rr = rel + (size_t)(row & 4095) * 512;
    o0 += rr[t]; o1 += rr[t + 256];
  }
  u16* orow = out + (size_t)row * 512;
  orow[t] = f2b(o0);
  orow[t + 256] = f2b(o1);
}

// ---------------- GEMM: C[M,N] = A[M,K] @ W[N,K]^T + bias, bf16 MFMA ----------------
// 3-buffer counted-vmcnt K-loop (T4): STAGE k+2 deep, vmcnt(4) per iter (never 0 mid-loop),
// ONE barrier per K-step. global_load_lds(16B), linear LDS. Vectorized LDS-park epilogue
// (LP=68 f32, 272B rows, 16B-aligned). Signature:
//   (A, W, bias, M, N, K, NBN, resid, outb, q_out, k_out, v_out, outf, gq, gk)
// EPI: 0 = qkv scatter + fused RMS on q/k (q_out/k_out/v_out)
//      1 = +residual -> f32 out (resid, outf)
//      2 = gelu -> bf16 out (outb)  ** outb MUST be non-null (round-10..13 crash) **
template<int EPI>
__global__ __launch_bounds__(256) void gemm_bt_kernel(
    const u16* __restrict__ A, const u16* __restrict__ W,
    const float* __restrict__ bias, int M, int N, int K, int NBN,
    const float* __restrict__ resid, u16* __restrict__ outb,
    u16* __restrict__ q_out, u16* __restrict__ k_out, u16* __restrict__ v_out,
    float* __restrict__ outf, const float* __restrict__ gq, const float* __restrict__ gk) {
  __shared__ __align__(16) u16 sbuf[24576];    // [3] A-slots (8KB ea) + [3] B-slots; park overlay
  int nwg = gridDim.x, wg = blockIdx.x;
  int wgs = (wg & 7) * (nwg >> 3) + (wg >> 3);     // XCD chunking (bijective: nwg%8==0)
  int bn = wgs % NBN, bm = wgs / NBN;
  int m0 = bm * 128, n0 = bn * 128;
  int t = threadIdx.x, lane = t & 63, wid = t >> 6;
  int wr = (wid >> 1) * 64, wc = (wid & 1) * 64;    // wave -> 64x64 quadrant
  int fr = lane & 15, fk = (lane >> 4) * 8;
  // staging: wave wid stages rows [wid*32, wid*32+32); chunk = 16 rows = 1KB.
  int srow = wid * 32 + (lane >> 2);
  int scol = (lane & 3) * 8;
  const u16* gA = A + (size_t)(m0 + srow) * K + scol;
  const u16* gB = W + (size_t)(n0 + srow) * K + scol;
  f32x4 acc[4][4] = {};
  auto AS = [&](int sel) { return &sbuf[sel * 4096]; };
  auto BS = [&](int sel) { return &sbuf[12288 + sel * 4096]; };
  auto STAGE = [&](int sel, int k0) {
    u16* lA = AS(sel) + wid * 1024;            // wave-uniform LDS base
    u16* lB = BS(sel) + wid * 1024;
    __builtin_amdgcn_global_load_lds(gA + k0,          lA,       16, 0, 0);
    __builtin_amdgcn_global_load_lds(gA + k0 + 16 * K, lA + 512, 16, 0, 0);
    __builtin_amdgcn_global_load_lds(gB + k0,          lB,       16, 0, 0);
    __builtin_amdgcn_global_load_lds(gB + k0 + 16 * K, lB + 512, 16, 0, 0);
  };
  // prologue: tiles 0,1 in flight (8 outstanding loads per wave)
  STAGE(0, 0);
  STAGE(1, 32);
  int cur = 0, nxt = 2;
  for (int k0 = 0; k0 < K; k0 += 32) {
    // tile k landed when my 4 oldest loads retire; tile k+1 (4 loads) stays in flight
    if (k0 + 32 < K) { asm volatile("s_waitcnt vmcnt(4)" ::: "memory"); }
    else             { asm volatile("s_waitcnt vmcnt(0)" ::: "memory"); }
    __builtin_amdgcn_s_barrier();   // all waves: tile k visible; tile k-1 reads finished
    if (k0 + 64 < K) {              // stage tile k+2 into the slot tile k-1 vacated
      STAGE(nxt, k0 + 64);
      nxt = (nxt == 2) ? 0 : nxt + 1;
    }
    bf16x8 af[4], bfr[4];
#pragma unroll
    for (int i = 0; i < 4; ++i) af[i] = *(const bf16x8*)&AS(cur)[(wr + i * 16 + fr) * 32 + fk];
#pragma unroll
    for (int j = 0; j < 4; ++j) bfr[j] = *(const bf16x8*)&BS(cur)[(wc + j * 16 + fr) * 32 + fk];
#pragma unroll
    for (int i = 0; i < 4; ++i)
#pragma unroll
      for (int j = 0; j < 4; ++j)
        acc[i][j] = __builtin_amdgcn_mfma_f32_16x16x32_bf16(af[i], bfr[j], acc[i][j], 0, 0, 0);
    cur = (cur == 2) ? 0 : cur + 1;
  }
  __syncthreads();   // separate last compute's ds_reads (all waves) from park writes
  // ---- Epilogue: park f32 in wave-private LDS, read back lane-contiguous ----
  int fq = lane >> 4;
  constexpr int LP = 68;                       // f32 row stride: 272B, 16B-aligned
  float* lbuf = (float*)sbuf + wid * 2048;     // 8KB per wave; 16x68 f32 = 4352B used
  float bv[4];
#pragma unroll
  for (int j = 0; j < 4; ++j) bv[j] = bias[n0 + wc + j * 16 + fr];
  int rr = lane >> 2, c0 = (lane & 3) * 16;    // readback: row rr, cols c0..c0+15
  // EPI==0 per-quadrant constants
  int nb = n0 + wc;
  int which = nb >> 9, head = (nb >> 6) & 7;
  float ggv[16];
  if (EPI == 0 && which != 2) {
    const float* gg = (which == 0) ? gq : gk;
#pragma unroll
    for (int e = 0; e < 16; ++e) ggv[e] = gg[head * 64 + c0 + e];
  }
#pragma unroll
  for (int i = 0; i < 4; ++i) {
#pragma unroll
    for (int j = 0; j < 4; ++j)
#pragma unroll
      for (int jj = 0; jj < 4; ++jj)
        lbuf[(fq * 4 + jj) * LP + j * 16 + fr] = acc[i][j][jj] + bv[j];
    // same-wave ds_write -> ds_read; compiler orders via lgkmcnt
    float v[16];
#pragma unroll
    for (int g = 0; g < 4; ++g) {
      f32x4 r4 = *(const f32x4*)&lbuf[rr * LP + c0 + g * 4];
#pragma unroll
      for (int e = 0; e < 4; ++e) v[g * 4 + e] = r4[e];
    }
    int gm = m0 + wr + i * 16 + rr;
    if (EPI == 0) {
      u16* dst = (which == 0) ? q_out : (which == 1) ? k_out : v_out;
      int b = gm >> 12, l = gm & 4095;
      size_t rowbase = (((size_t)(b * 8 + head) * 4096) + l) * 64 + c0;
      union { u16 h[16]; uint4 q[2]; } pk;
      if (which == 2) {
#pragma unroll
        for (int e = 0; e < 16; ++e) pk.h[e] = cvt_bf16(v[e]);
      } else {
        float ssum = 0.f;
#pragma unroll
        for (int e = 0; e < 16; ++e) ssum += v[e] * v[e];
        ssum += __shfl_xor(ssum, 1);
        ssum += __shfl_xor(ssum, 2);               // row-sum within 4-lane group
        float inv = 8.0f / fmaxf(sqrtf(ssum), 1e-12f);
#pragma unroll
        for (int e = 0; e < 16; ++e) pk.h[e] = cvt_bf16(v[e] * inv * ggv[e]);
      }
      *(uint4*)&dst[rowbase] = pk.q[0];
      *(uint4*)&dst[rowbase + 8] = pk.q[1];
    } else if (EPI == 1) {
      size_t idx = (size_t)gm * 512 + n0 + wc + c0;
#pragma unroll
      for (int g = 0; g < 4; ++g) {
        f32x4 r = *(const f32x4*)&resid[idx + g * 4];
        f32x4 o;
#pragma unroll
        for (int e = 0; e < 4; ++e) o[e] = v[g * 4 + e] + r[e];
        *(f32x4*)&outf[idx + g * 4] = o;
      }
    } else {  // EPI == 2: gelu -> bf16
      union { u16 h[16]; uint4 q[2]; } pk;
#pragma unroll
      for (int e = 0; e < 16; ++e) pk.h[e] = cvt_bf16(fast_gelu(v[e]));
      size_t idx = (size_t)gm * (size_t)N + n0 + wc + c0;
      *(uint4*)&outb[idx] = pk.q[0];
      *(uint4*)&outb[idx + 8] = pk.q[1];
    }
  }
}

// ---------------- Attention pass 1: per-chunk kv partial P_c = (k*kdec)^T @ v ----------------
// grid 1024 = bh*32 + c. Output P[bid] as f32 64x64 in (e, dd) layout.
__global__ __launch_bounds__(256) void attn_kv_kernel(
    const u16* __restrict__ k, const u16* __restrict__ v, float* __restrict__ P) {
  constexpr int LT = 136;
  __shared__ __align__(16) u16 kT_s[64 * LT];
  __shared__ __align__(16) u16 vT_s[64 * LT];
  __shared__ float kdec[128];
  int bid = blockIdx.x;
  int bh = bid >> 5;
  float sl = exp2f(-(float)((bh & 7) + 1));
  int t = threadIdx.x, lane = t & 63, wid = t >> 6;
  for (int i = t; i < 128; i += 256) kdec[i] = expf(-sl * (float)(128 - i));
  const u16* kb = k + (size_t)bid * 8192;
  const u16* vb = v + (size_t)bid * 8192;
  __syncthreads();
  int fr = lane & 15, fk = (lane >> 4) * 8, fq = lane >> 4;
#pragma unroll
  for (int i = 0; i < 16; ++i) {
    int seg = t + i * 256;
    int j = seg >> 5, dd = (seg & 31) * 2;
    unsigned int kp = *(const unsigned int*)&kb[(size_t)j * 64 + dd];
    float kd = kdec[j];
    kT_s[dd * LT + j] = f2b(b2f((u16)(kp & 0xFFFFu)) * kd);
    kT_s[(dd + 1) * LT + j] = f2b(b2f((u16)(kp >> 16)) * kd);
    unsigned int vp = *(const unsigned int*)&vb[(size_t)j * 64 + dd];
    vT_s[dd * LT + j] = (u16)(vp & 0xFFFFu);
    vT_s[(dd + 1) * LT + j] = (u16)(vp >> 16);
  }
  __syncthreads();
  f32x4 accKV[4] = {};
#pragma unroll
  for (int kk = 0; kk < 4; ++kk) {
    bf16x8 akt = *(const bf16x8*)&kT_s[(wid * 16 + fr) * LT + kk * 32 + fk];
#pragma unroll
    for (int j = 0; j < 4; ++j) {
      bf16x8 bvt = *(const bf16x8*)&vT_s[(j * 16 + fr) * LT + kk * 32 + fk];
      accKV[j] = __builtin_amdgcn_mfma_f32_16x16x32_bf16(akt, bvt, accKV[j], 0, 0, 0);
    }
  }
  // park P^T (e, dd) into f32 LDS (overlay kT_s), stride 68 to spread banks
  float* PT = (float*)kT_s;      // 64*68*4 = 17408 B <= kT_s 34816 B
  __syncthreads();
#pragma unroll
  for (int j = 0; j < 4; ++j)
#pragma unroll
    for (int jj = 0; jj < 4; ++jj) {
      int dd = wid * 16 + fq * 4 + jj;
      int e = j * 16 + fr;
      PT[e * 68 + dd] = accKV[j][jj];
    }
  __syncthreads();
  float* Pg = P + (size_t)bid * 4096;
  int e = t >> 2, d0 = (t & 3) * 16;
#pragma unroll
  for (int g = 0; g < 4; ++g) {
    f32x4 val = *(const f32x4*)&PT[e * 68 + d0 + g * 4];
    *(f32x4*)&Pg[(size_t)e * 64 + d0 + g * 4] = val;
  }
}

// ---------------- Attention pass 2: scan kv state; emit pre-chunk state as bf16 (e,d) ----------------
__global__ __launch_bounds__(256) void attn_scan_kernel(
    const float* __restrict__ P, u16* __restrict__ kvst) {
  int bh = blockIdx.x, t = threadIdx.x;
  float sl = exp2f(-(float)((bh & 7) + 1));
  float cdec = expf(-sl * 128.0f);
  float kv[16];
#pragma unroll
  for (int i = 0; i < 16; ++i) kv[i] = 0.f;
  for (int c = 0; c < 32; ++c) {
    size_t off = (((size_t)bh * 32 + c) * 4096) + (size_t)t * 16;
    union { u16 st[16]; uint4 v4[4]; } u;
#pragma unroll
    for (int i = 0; i < 16; ++i) u.st[i] = f2b(kv[i]);
    *(uint4*)&kvst[off] = u.v4[0];
    *(uint4*)&kvst[off + 8] = u.v4[1];
#pragma unroll
    for (int g = 0; g < 4; ++g) {
      f32x4 p = *(const f32x4*)&P[off + g * 4];
#pragma unroll
      for (int e = 0; e < 4; ++e) kv[g * 4 + e] = cdec * kv[g * 4 + e] + p[e];
    }
  }
}

// ---------------- Attention pass 3: out_c = masked(QK^T)@V + qdec*(Q@kv_state) ----------------
__global__ __launch_bounds__(256) void attn_out_kernel(
    const u16* __restrict__ q, const u16* __restrict__ k, const u16* __restrict__ v,
    const u16* __restrict__ kvst, u16* __restrict__ o) {
  constexpr int LQ = 72, LT = 136, LS = 136, LKV = 72;
  __shared__ __align__(16) u16 sm[31744];
  u16* q_s  = sm;              // 128*72
  u16* k_s  = sm + 9216;       // 128*72
  u16* vT_s = sm + 18432;      // 64*136
  u16* kvT_s = sm + 27136;     // 64*72
  u16* S_s  = sm;              // 128*136 overlays q_s+k_s (dead after S/inter MFMA)
  __shared__ float rowf[128], colf[128];
  int bid = blockIdx.x;
  int bh = bid >> 5;
  float sl = exp2f(-(float)((bh & 7) + 1));
  int t = threadIdx.x, lane = t & 63, wid = t >> 6;
  for (int i = t; i < 128; i += 256) {
    rowf[i] = expf(-sl * i);
    colf[i] = expf(sl * i);
  }
  const u16* qb = q + (size_t)bid * 8192;
  const u16* kb = k + (size_t)bid * 8192;
  const u16* vb = v + (size_t)bid * 8192;
  const u16* kvb = kvst + (size_t)bid * 4096;
  u16* ob = o + (size_t)bid * 8192;
  int fr = lane & 15, fk = (lane >> 4) * 8, fq = lane >> 4;
#pragma unroll
  for (int i = 0; i < 4; ++i) {        // q,k row-major
    int seg = t + i * 256;
    int r = seg >> 3, cc = (seg & 7) * 8;
    *(uint4*)&q_s[r * LQ + cc] = *(const uint4*)&qb[(size_t)r * 64 + cc];
    *(uint4*)&k_s[r * LQ + cc] = *(const uint4*)&kb[(size_t)r * 64 + cc];
  }
#pragma unroll
  for (int i = 0; i < 16; ++i) {       // vT transpose
    int seg = t + i * 256;
    int j = seg >> 5, dd = (seg & 31) * 2;
    unsigned int vp = *(const unsigned int*)&vb[(size_t)j * 64 + dd];
    vT_s[dd * LT + j] = (u16)(vp & 0xFFFFu);
    vT_s[(dd + 1) * LT + j] = (u16)(vp >> 16);
  }
#pragma unroll
  for (int i = 0; i < 2; ++i) {        // kv state straight copy (already (e,d))
    int seg = t + i * 256;
    int e = seg >> 3, dd = (seg & 7) * 8;
    *(uint4*)&kvT_s[e * LKV + dd] = *(const uint4*)&kvb[(size_t)e * 64 + dd];
  }
  __syncthreads();
  // S = Q K^T and inter = Q @ kv  (wave owns q-rows [wid*32, +32))
  f32x4 accS[2][8] = {};
  f32x4 accI[2][4] = {};
#pragma unroll
  for (int kk = 0; kk < 2; ++kk) {
    bf16x8 aq0 = *(const bf16x8*)&q_s[(wid * 32 + fr) * LQ + kk * 32 + fk];
    bf16x8 aq1 = *(const bf16x8*)&q_s[(wid * 32 + 16 + fr) * LQ + kk * 32 + fk];
#pragma unroll
    for (int j = 0; j < 8; ++j) {
      bf16x8 bk = *(const bf16x8*)&k_s[(j * 16 + fr) * LQ + kk * 32 + fk];
      accS[0][j] = __builtin_amdgcn_mfma_f32_16x16x32_bf16(aq0, bk, accS[0][j], 0, 0, 0);
      accS[1][j] = __builtin_amdgcn_mfma_f32_16x16x32_bf16(aq1, bk, accS[1][j], 0, 0, 0);
    }
#pragma unroll
    for (int j = 0; j < 4; ++j) {
      bf16x8 bkv = *(const bf16x8*)&kvT_s[(j * 16 + fr) * LKV + kk * 32 + fk];
      accI[0][j] = __builtin_amdgcn_mfma_f32_16x16x32_bf16(aq0, bkv, accI[0][j], 0, 0, 0);
      accI[1][j] = __builtin_amdgcn_mfma_f32_16x16x32_bf16(aq1, bkv, accI[1][j], 0, 0, 0);
    }
  }
  __syncthreads();   // q_s,k_s now dead -> S_s region reusable
#pragma unroll
  for (int i = 0; i < 2; ++i)
#pragma unroll
    for (int j = 0; j < 8; ++j)
#pragma unroll
      for (int jj = 0; jj < 4; ++jj) {
        int si = wid * 32 + i * 16 + fq * 4 + jj;
        int sj = j * 16 + fr;
        float val = (si >= sj) ? accS[i][j][jj] * rowf[si] * colf[sj] : 0.0f;
        S_s[si * LS + sj] = f2b(val);
      }
  __syncthreads();
  // intra = S' @ V
  f32x4 accO[2][4] = {};
#pragma unroll
  for (int kk = 0; kk < 4; ++kk) {
    bf16x8 as0 = *(const bf16x8*)&S_s[(wid * 32 + fr) * LS + kk * 32 + fk];
    bf16x8 as1 = *(const bf16x8*)&S_s[(wid * 32 + 16 + fr) * LS + kk * 32 + fk];
#pragma unroll
    for (int j = 0; j < 4; ++j) {
      bf16x8 bvt = *(const bf16x8*)&vT_s[(j * 16 + fr) * LT + kk * 32 + fk];
      accO[0][j] = __builtin_amdgcn_mfma_f32_16x16x32_bf16(as0, bvt, accO[0][j], 0, 0, 0);
      accO[1][j] = __builtin_amdgcn_mfma_f32_16x16x32_bf16(as1, bvt, accO[1][j], 0, 0, 0);
    }
  }
#pragma unroll
  for (int i = 0; i < 2; ++i)
#pragma unroll
    for (int j = 0; j < 4; ++j)
#pragma unroll
      for (int jj = 0; jj < 4; ++jj) {
        int li = wid * 32 + i * 16 + fq * 4 + jj;
        int e = j * 16 + fr;
        float val = accO[i][j][jj] + rowf[li] * accI[i][j][jj];
        ob[(size_t)li * 64 + e] = f2b(val);
      }
}

extern "C" void kernel_launch(void* const* d_in, const int* in_sizes, int n_in,
                              void* d_out, int out_size, void* d_ws, size_t ws_size,
                              hipStream_t stream) {
  const float* x      = (const float*)d_in[0];
  const float* ln1_w  = (const float*)d_in[1];
  const float* ln1_b  = (const float*)d_in[2];
  const float* rel    = (const float*)d_in[3];
  const float* qkv_w  = (const float*)d_in[4];
  const float* qkv_b  = (const float*)d_in[5];
  const float* gq     = (const float*)d_in[6];
  const float* gk     = (const float*)d_in[7];
  const float* proj_w = (const float*)d_in[8];
  const float* proj_b = (const float*)d_in[9];
  const float* ln2_w  = (const float*)d_in[10];
  const float* ln2_b  = (const float*)d_in[11];
  const float* fc1_w  = (const float*)d_in[12];
  const float* fc1_b  = (const float*)d_in[13];
  const float* fc2_w  = (const float*)d_in[14];
  const float* fc2_b  = (const float*)d_in[15];

  char* ws = (char*)d_ws;
  size_t off = 0;
  auto alloc = [&](size_t bytes) { char* p = ws + off; off += (bytes + 255) & ~(size_t)255; return p; };
  u16* w_qkv  = (u16*)alloc((size_t)1536 * 512 * 2);
  u16* w_proj = (u16*)alloc((size_t)512 * 512 * 2);
  u16* w_fc1  = (u16*)alloc((size_t)2048 * 512 * 2);
  u16* w_fc2  = (u16*)alloc((size_t)512 * 2048 * 2);
  u16* h_buf  = (u16*)alloc((size_t)16384 * 512 * 2);   // ln1 out; reused for ln2 out
  u16* q_buf  = (u16*)alloc((size_t)8388608 * 2);
  u16* k_buf  = (u16*)alloc((size_t)8388608 * 2);
  u16* v_buf  = (u16*)alloc((size_t)8388608 * 2);
  u16* o_buf  = (u16*)alloc((size_t)8388608 * 2);
  float* x2   = (float*)alloc((size_t)8388608 * 4);
  u16* mid    = q_buf;   // 16384x2048 bf16 overlays q..o (dead after attention/proj)
  // attention scratch overlays x2 (x2 written only after attention):
  float* P_glob  = x2;                       // 1024*4096 f32 = 16.8 MB
  u16*   kv_state = (u16*)(x2 + 4194304);    // 1024*4096 bf16 = 8.4 MB

  conv4_kernel<<<1024, 256, 0, stream>>>(qkv_w, w_qkv, 1536 * 512,
                                         proj_w, w_proj, 512 * 512,
                                         fc1_w, w_fc1, 2048 * 512,
                                         fc2_w, w_fc2, 512 * 2048);

  ln_kernel<1><<<16384, 256, 0, stream>>>(x, ln1_w, ln1_b, rel, h_buf);

  // (A, W, bias, M, N, K, NBN, resid, outb, q_out, k_out, v_out, outf, gq, gk)
  gemm_bt_kernel<0><<<1536, 256, 0, stream>>>(h_buf, w_qkv, qkv_b, 16384, 1536, 512, 12,
      /*resid*/nullptr, /*outb*/nullptr, /*q*/q_buf, /*k*/k_buf, /*v*/v_buf,
      /*outf*/nullptr, gq, gk);

  attn_kv_kernel<<<1024, 256, 0, stream>>>(k_buf, v_buf, P_glob);
  attn_scan_kernel<<<32, 256, 0, stream>>>(P_glob, kv_state);
  attn_out_kernel<<<1024, 256, 0, stream>>>(q_buf, k_buf, v_buf, kv_state, o_buf);

  gemm_bt_kernel<1><<<512, 256, 0, stream>>>(o_buf, w_proj, proj_b, 16384, 512, 512, 4,
      /*resid*/x, /*outb*/nullptr, nullptr, nullptr, nullptr, /*outf*/x2, nullptr, nullptr);

  ln_kernel<0><<<16384, 256, 0, stream>>>(x2, ln2_w, ln2_b, nullptr, h_buf);

  gemm_bt_kernel<2><<<2048, 256, 0, stream>>>(h_buf, w_fc1, fc1_b, 16384, 2048, 512, 16,
      /*resid*/nullptr, /*outb*/mid, nullptr, nullptr, nullptr, /*outf*/nullptr, nullptr, nullptr);

  gemm_bt_kernel<1><<<512, 256, 0, stream>>>(mid, w_fc2, fc2_b, 16384, 512, 2048, 4,
      /*resid*/x2, /*outb*/nullptr, nullptr, nullptr, nullptr, /*outf*/(float*)d_out, nullptr, nullptr);

  (void)in_sizes; (void)n_in; (void)out_size; (void)ws_size;
}